// Round 5
// baseline (582.554 us; speedup 1.0000x reference)
//
#include <hip/hip_runtime.h>

typedef __attribute__((ext_vector_type(8))) short short8;
typedef __attribute__((ext_vector_type(4))) float f32x4;

__device__ __forceinline__ unsigned short f2bf(float f) {
    unsigned u = __float_as_uint(f);
    u += 0x7FFFu + ((u >> 16) & 1u);
    return (unsigned short)(u >> 16);
}
__device__ __forceinline__ float bf2f(unsigned short h) {
    return __uint_as_float((unsigned)h << 16);
}

// =====================================================================
// gemm_direct: C[M,Nb] = A[M,K]@B[K,Nb] (+bias)(*rowscale), A f32 -> bf16 direct-to-reg,
// B staged in padded LDS (conflict-free). MF m-frags/wave (BM = 64*MF). 256 thr = 4 waves.
// If fin_den != nullptr: C[idx] = relu(C[idx]/den + acc)  (fused GAT finalize, f32 only)
template<bool OBF16, int MF>
__global__ __launch_bounds__(256)
void gemm_direct(const float* __restrict__ A, const float* __restrict__ B,
                 const float* __restrict__ bias, const float* __restrict__ rowscale,
                 void* __restrict__ Cv, const float* __restrict__ fin_den,
                 int M, int Nb, int K, int ldc, int ccol)
{
    constexpr int BPS = 64 * 8 + 8;   // padded plane stride (shorts): 1040 B = 4 dwords mod 32
    __shared__ alignas(16) unsigned short Bl[4 * BPS];
    const int t = threadIdx.x;
    const int w = t >> 6, l = t & 63;
    const int r16 = l & 15, kg = l >> 4;
    const int row0 = blockIdx.x * (64 * MF);
    const int col0 = blockIdx.y * 64;

    const float* ar[MF];
    bool va[MF];
#pragma unroll
    for (int mi = 0; mi < MF; ++mi) {
        int gm = row0 + (w * MF + mi) * 16 + r16;
        va[mi] = gm < M;
        ar[mi] = A + (size_t)gm * K + kg * 8;
    }
    f32x4 acc[MF][4] = {};
    const float4 fz = make_float4(0.f, 0.f, 0.f, 0.f);
    float4 pa0[MF], pa1[MF];
#pragma unroll
    for (int mi = 0; mi < MF; ++mi) {
        pa0[mi] = va[mi] ? *reinterpret_cast<const float4*>(ar[mi]) : fz;
        pa1[mi] = va[mi] ? *reinterpret_cast<const float4*>(ar[mi] + 4) : fz;
    }
    for (int k0 = 0; k0 < K; k0 += 32) {
        // stage B chunk (32k x 64n) transposed to fragment layout, bf16
        if (t < 128) {
            int kb = (t >> 4) * 4, cb = (t & 15) * 4;
            const float* bp = B + (size_t)(k0 + kb) * Nb + col0 + cb;
            float4 r0 = *reinterpret_cast<const float4*>(bp);
            float4 r1 = *reinterpret_cast<const float4*>(bp + Nb);
            float4 r2 = *reinterpret_cast<const float4*>(bp + 2 * (size_t)Nb);
            float4 r3 = *reinterpret_cast<const float4*>(bp + 3 * (size_t)Nb);
            int g = kb >> 3, hh = (kb >> 2) & 1;
            unsigned short* bb = &Bl[g * BPS + cb * 8 + hh * 4];
            *reinterpret_cast<ushort4*>(bb +  0) = make_ushort4(f2bf(r0.x), f2bf(r1.x), f2bf(r2.x), f2bf(r3.x));
            *reinterpret_cast<ushort4*>(bb +  8) = make_ushort4(f2bf(r0.y), f2bf(r1.y), f2bf(r2.y), f2bf(r3.y));
            *reinterpret_cast<ushort4*>(bb + 16) = make_ushort4(f2bf(r0.z), f2bf(r1.z), f2bf(r2.z), f2bf(r3.z));
            *reinterpret_cast<ushort4*>(bb + 24) = make_ushort4(f2bf(r0.w), f2bf(r1.w), f2bf(r2.w), f2bf(r3.w));
        }
        __syncthreads();
        float4 c0[MF], c1[MF];
#pragma unroll
        for (int mi = 0; mi < MF; ++mi) { c0[mi] = pa0[mi]; c1[mi] = pa1[mi]; }
        if (k0 + 32 < K) {
#pragma unroll
            for (int mi = 0; mi < MF; ++mi) {
                pa0[mi] = va[mi] ? *reinterpret_cast<const float4*>(ar[mi] + k0 + 32) : fz;
                pa1[mi] = va[mi] ? *reinterpret_cast<const float4*>(ar[mi] + k0 + 36) : fz;
            }
        }
        short8 ah[MF];
#pragma unroll
        for (int mi = 0; mi < MF; ++mi) {
            float av[8] = {c0[mi].x, c0[mi].y, c0[mi].z, c0[mi].w,
                           c1[mi].x, c1[mi].y, c1[mi].z, c1[mi].w};
#pragma unroll
            for (int j = 0; j < 8; ++j) ah[mi][j] = (short)f2bf(av[j]);
        }
#pragma unroll
        for (int ni = 0; ni < 4; ++ni) {
            short8 bf = *reinterpret_cast<const short8*>(&Bl[kg * BPS + (ni * 16 + r16) * 8]);
#pragma unroll
            for (int mi = 0; mi < MF; ++mi)
                acc[mi][ni] = __builtin_amdgcn_mfma_f32_16x16x32_bf16(ah[mi], bf, acc[mi][ni], 0, 0, 0);
        }
        __syncthreads();
    }
#pragma unroll
    for (int mi = 0; mi < MF; ++mi)
#pragma unroll
        for (int ni = 0; ni < 4; ++ni) {
            int col = col0 + ni * 16 + r16;
            float bv = bias ? bias[col] : 0.f;
#pragma unroll
            for (int r = 0; r < 4; ++r) {
                int gm = row0 + (w * MF + mi) * 16 + kg * 4 + r;
                if (gm < M) {
                    float val = acc[mi][ni][r] + bv;
                    if (rowscale) val *= rowscale[gm];
                    size_t idx = (size_t)gm * ldc + ccol + col;
                    if (OBF16) {
                        ((unsigned short*)Cv)[idx] = f2bf(val);
                    } else if (fin_den) {
                        float d = fin_den[(size_t)gm * 16 + (col >> 5)];
                        float inv = (d > 0.f) ? __fdividef(1.f, d) : 0.f;
                        float* cp = (float*)Cv;
                        cp[idx] = fmaxf(cp[idx] * inv + val, 0.f);
                    } else {
                        ((float*)Cv)[idx] = val;
                    }
                }
            }
        }
}

// =====================================================================
// encoder: bf16x3 split-precision MFMA, A direct-to-reg, B (weights) in padded LDS hi/lo.
// BM=32: wave w -> m-frag (w&1), col half (w>>1). grid (M/32, 1, 3)
__global__ __launch_bounds__(256)
void enc_mfma2(const float* __restrict__ text, const float* __restrict__ audio, const float* __restrict__ vision,
               const float* __restrict__ Wt, const float* __restrict__ Wa, const float* __restrict__ Wv,
               const float* __restrict__ bt, const float* __restrict__ ba, const float* __restrict__ bv,
               float* __restrict__ C, int M)
{
    constexpr int BPS = 64 * 8 + 8;
    __shared__ alignas(16) unsigned short Bh[4 * BPS], Bo[4 * BPS];
    const int z = blockIdx.z;
    const float* A  = (z == 0) ? text : (z == 1) ? audio : vision;
    const float* W  = (z == 0) ? Wt   : (z == 1) ? Wa    : Wv;
    const float* bb = (z == 0) ? bt   : (z == 1) ? ba    : bv;
    const int K = (z == 1) ? 512 : 1024;

    const int t = threadIdx.x;
    const int w = t >> 6, l = t & 63;
    const int r16 = l & 15, kg = l >> 4;
    const int row0 = blockIdx.x * 32;
    const int gm = row0 + (w & 1) * 16 + r16;
    const int ncol0 = (w >> 1) * 32;
    const float* arow = A + (size_t)gm * K + kg * 8;
    f32x4 acc[2] = {};
    float4 nA = *reinterpret_cast<const float4*>(arow);
    float4 nB = *reinterpret_cast<const float4*>(arow + 4);
    for (int k0 = 0; k0 < K; k0 += 32) {
        if (t < 128) {
            int kb = (t >> 4) * 4, cb = (t & 15) * 4;
            const float* bp = W + (size_t)(k0 + kb) * 64 + cb;
            float4 r0 = *reinterpret_cast<const float4*>(bp);
            float4 r1 = *reinterpret_cast<const float4*>(bp + 64);
            float4 r2 = *reinterpret_cast<const float4*>(bp + 128);
            float4 r3 = *reinterpret_cast<const float4*>(bp + 192);
            int g = kb >> 3, hh = (kb >> 2) & 1;
            float cc[4][4] = {{r0.x, r1.x, r2.x, r3.x}, {r0.y, r1.y, r2.y, r3.y},
                              {r0.z, r1.z, r2.z, r3.z}, {r0.w, r1.w, r2.w, r3.w}};
#pragma unroll
            for (int j = 0; j < 4; ++j) {
                ushort4 hi = make_ushort4(f2bf(cc[j][0]), f2bf(cc[j][1]), f2bf(cc[j][2]), f2bf(cc[j][3]));
                ushort4 lo = make_ushort4(f2bf(cc[j][0] - bf2f(hi.x)), f2bf(cc[j][1] - bf2f(hi.y)),
                                          f2bf(cc[j][2] - bf2f(hi.z)), f2bf(cc[j][3] - bf2f(hi.w)));
                *reinterpret_cast<ushort4*>(&Bh[g * BPS + (cb + j) * 8 + hh * 4]) = hi;
                *reinterpret_cast<ushort4*>(&Bo[g * BPS + (cb + j) * 8 + hh * 4]) = lo;
            }
        }
        __syncthreads();
        float4 cA = nA, cB = nB;
        if (k0 + 32 < K) {
            nA = *reinterpret_cast<const float4*>(arow + k0 + 32);
            nB = *reinterpret_cast<const float4*>(arow + k0 + 36);
        }
        float av[8] = {cA.x, cA.y, cA.z, cA.w, cB.x, cB.y, cB.z, cB.w};
        short8 ah, ao;
#pragma unroll
        for (int j = 0; j < 8; ++j) {
            unsigned short h = f2bf(av[j]);
            ah[j] = (short)h;
            ao[j] = (short)f2bf(av[j] - bf2f(h));
        }
#pragma unroll
        for (int ni = 0; ni < 2; ++ni) {
            int cidx = kg * BPS + (ncol0 + ni * 16 + r16) * 8;
            short8 bhv = *reinterpret_cast<const short8*>(&Bh[cidx]);
            short8 bov = *reinterpret_cast<const short8*>(&Bo[cidx]);
            acc[ni] = __builtin_amdgcn_mfma_f32_16x16x32_bf16(ah, bhv, acc[ni], 0, 0, 0);
            acc[ni] = __builtin_amdgcn_mfma_f32_16x16x32_bf16(ah, bov, acc[ni], 0, 0, 0);
            acc[ni] = __builtin_amdgcn_mfma_f32_16x16x32_bf16(ao, bhv, acc[ni], 0, 0, 0);
        }
        __syncthreads();
    }
#pragma unroll
    for (int ni = 0; ni < 2; ++ni) {
        int col = ncol0 + ni * 16 + r16;
        float bvv = bb[col];
#pragma unroll
        for (int r = 0; r < 4; ++r) {
            int gr = row0 + (w & 1) * 16 + kg * 4 + r;
            if (gr < M) C[(size_t)gr * 192 + z * 64 + col] = acc[ni][r] + bvv;
        }
    }
}

// ---------------- weight packing
__global__ void pack3_kernel(const float* __restrict__ W0, const float* __restrict__ W1, const float* __restrict__ W2,
                             const float* __restrict__ b0, const float* __restrict__ b1,
                             float* __restrict__ Wp, float* __restrict__ bp, int K, int O)
{
    int gid = blockIdx.x * blockDim.x + threadIdx.x;
    int O3 = 3 * O;
    if (gid < O3) bp[gid] = (gid < O) ? b0[gid] : (gid < 2 * O) ? b1[gid - O] : 0.f;
    if (gid >= K * O3) return;
    int k = gid / O3, c = gid - k * O3;
    float v = (c < O) ? W0[k * O + c] : (c < 2 * O) ? W1[k * O + c - O] : W2[k * O + c - 2 * O];
    Wp[gid] = v;
}

__global__ void pack2_kernel(const float* __restrict__ W0, const float* __restrict__ W1,
                             const float* __restrict__ b0, const float* __restrict__ b1,
                             float* __restrict__ Wp, float* __restrict__ bp, int K, int O)
{
    int gid = blockIdx.x * blockDim.x + threadIdx.x;
    int O2 = 2 * O;
    if (gid < O2) bp[gid] = (gid < O) ? b0[gid] : b1[gid - O];
    if (gid >= K * O2) return;
    int k = gid / O2, c = gid - k * O2;
    Wp[gid] = (c < O) ? W0[k * O + c] : W1[k * O + c - O];
}

// ---------------- graph preprocessing
__global__ void deg_kernel(const int* __restrict__ src, const int* __restrict__ dst,
                           int* degout, int* degin, int E)
{
    int e = blockIdx.x * blockDim.x + threadIdx.x;
    if (e < E) {
        atomicAdd(&degout[src[e]], 1);
        atomicAdd(&degin[dst[e]], 1);
    }
}

__global__ __launch_bounds__(1024)
void scan_kernel(const int* __restrict__ degin, int* __restrict__ rowstart, int n)
{
    __shared__ int part[1024];
    int t = threadIdx.x;
    int chunk = (n + 1023) / 1024;
    int s = 0;
    for (int i = 0; i < chunk; ++i) {
        int idx = t * chunk + i;
        if (idx < n) s += degin[idx];
    }
    part[t] = s;
    __syncthreads();
    for (int o = 1; o < 1024; o <<= 1) {
        int v = (t >= o) ? part[t - o] : 0;
        __syncthreads();
        part[t] += v;
        __syncthreads();
    }
    int run = (t > 0) ? part[t - 1] : 0;
    for (int i = 0; i < chunk; ++i) {
        int idx = t * chunk + i;
        if (idx < n) { rowstart[idx] = run; run += degin[idx]; }
    }
    if (t == 1023) rowstart[n] = part[1023];
}

__global__ void perm_kernel(const int* __restrict__ dst, const int* __restrict__ rowstart,
                            int* cursor, int* __restrict__ perm, int E)
{
    int e = blockIdx.x * blockDim.x + threadIdx.x;
    if (e < E) {
        int v = dst[e];
        int p = atomicAdd(&cursor[v], 1);
        perm[rowstart[v] + p] = e;
    }
}

__global__ void gather_src_kernel(const int* __restrict__ esrc, int* perm, int E)
{
    int i = blockIdx.x * blockDim.x + threadIdx.x;
    if (i < E) perm[i] = esrc[perm[i]];
}

__global__ void rs_kernel(const int* degout, const int* degin, float* rso, float* rsi, int n)
{
    int i = blockIdx.x * blockDim.x + threadIdx.x;
    if (i < n) {
        rso[i] = rsqrtf((float)max(degout[i], 1));
        rsi[i] = rsqrtf((float)max(degin[i], 1));
    }
}

// ---------------- LSTM
__global__ void lstm_pre(const float* __restrict__ x, const float* __restrict__ Wf,
                         const float* __restrict__ Wb,
                         const float* bf1, const float* bf2, const float* bb1, const float* bb2,
                         float* __restrict__ xWf, float* __restrict__ xWb, int n)
{
    int gid = blockIdx.x * blockDim.x + threadIdx.x;
    if (gid >= n * 32) return;
    int nn = gid >> 5, r = gid & 31, d = r >> 4, j = r & 15;
    const float* W = (d ? Wb : Wf) + j * 192;
    const float* xr = x + (size_t)nn * 192;
    float s = 0.f;
#pragma unroll 4
    for (int k = 0; k < 192; k += 4) {
        float4 xv = *reinterpret_cast<const float4*>(xr + k);
        float4 wv = *reinterpret_cast<const float4*>(W + k);
        s += xv.x * wv.x + xv.y * wv.y + xv.z * wv.z + xv.w * wv.w;
    }
    s += d ? (bb1[j] + bb2[j]) : (bf1[j] + bf2[j]);
    int b = nn / 120, tt = nn - b * 120;
    (d ? xWb : xWf)[((size_t)b * 16 + j) * 120 + tt] = s;
}

__device__ __forceinline__ float fsigm(float x) { return __fdividef(1.f, 1.f + __expf(-x)); }
__device__ __forceinline__ float ftanh(float x) { return 1.f - __fdividef(2.f, __expf(2.f * x) + 1.f); }

template<int DIR>
__device__ void lstm_chain(const float* __restrict__ xw, const float* __restrict__ whh,
                           float* __restrict__ newF, int b)
{
    int j = threadIdx.x & 15;
    int k = j & 3;
    float4 w = *reinterpret_cast<const float4*>(whh + j * 4);
    const float* xp = xw + ((size_t)b * 16 + j) * 120;
    float h0 = 0.f, h1 = 0.f, h2 = 0.f, h3 = 0.f, cst = 0.f;
    int tb0 = DIR ? 108 : 0;
    float4 a0 = *reinterpret_cast<const float4*>(xp + tb0);
    float4 a1 = *reinterpret_cast<const float4*>(xp + tb0 + 4);
    float4 a2 = *reinterpret_cast<const float4*>(xp + tb0 + 8);
    for (int ch = 0; ch < 10; ++ch) {
        float4 b0 = a0, b1 = a1, b2 = a2;
        if (ch < 9) {
            int nt = DIR ? (96 - ch * 12) : (12 + ch * 12);
            b0 = *reinterpret_cast<const float4*>(xp + nt);
            b1 = *reinterpret_cast<const float4*>(xp + nt + 4);
            b2 = *reinterpret_cast<const float4*>(xp + nt + 8);
        }
        float zz[12] = {a0.x, a0.y, a0.z, a0.w, a1.x, a1.y, a1.z, a1.w, a2.x, a2.y, a2.z, a2.w};
        int tbase = DIR ? (108 - ch * 12) : (ch * 12);
#pragma unroll
        for (int ii = 0; ii < 12; ++ii) {
            int idx = DIR ? (11 - ii) : ii;
            float z = zz[idx] + ((w.x * h0 + w.y * h1) + (w.z * h2 + w.w * h3));
            float zi = __shfl(z, k, 16);
            float zf = __shfl(z, k + 4, 16);
            float zg = __shfl(z, k + 8, 16);
            float zo = __shfl(z, k + 12, 16);
            float ig = fsigm(zi), fg = fsigm(zf), gg = ftanh(zg), og = fsigm(zo);
            cst = fg * cst + ig * gg;
            float hn = og * ftanh(cst);
            h0 = __shfl(hn, 0, 16); h1 = __shfl(hn, 1, 16);
            h2 = __shfl(hn, 2, 16); h3 = __shfl(hn, 3, 16);
            if (j < 4) newF[((size_t)b * 120 + tbase + idx) * 8 + DIR * 4 + j] = hn;
        }
        a0 = b0; a1 = b1; a2 = b2;
    }
}

__global__ __launch_bounds__(64)
void lstm_seq2(const float* __restrict__ xWf, const float* __restrict__ xWb,
               const float* __restrict__ Whhf, const float* __restrict__ Whhb,
               float* __restrict__ newF, int B)
{
    int sub = threadIdx.x >> 4;
    int chain = blockIdx.x * 4 + sub;
    if (chain >= 2 * B) return;
    int d = chain / B;
    int b = chain - d * B;
    if (d == 0) lstm_chain<0>(xWf, Whhf, newF, b);
    else        lstm_chain<1>(xWb, Whhb, newF, b);
}

// ---------------- GraphConv combine + L1 norm: one wave per node, 3 feats/lane
__global__ __launch_bounds__(256)
void gc_combine2(const float* __restrict__ stackFT, const float* __restrict__ hw,
                 const int* __restrict__ rowstart, const int* __restrict__ csrc,
                 const float* __restrict__ rs_in,
                 const float* __restrict__ b_gc, float* __restrict__ h, int n)
{
    int v = blockIdx.x * 4 + (threadIdx.x >> 6);
    int l = threadIdx.x & 63;
    if (v >= n) return;
    int s0 = rowstart[v], s1 = rowstart[v + 1];
    float sum0 = 0.f, sum1 = 0.f, sum2 = 0.f;
    int u = (s0 < s1) ? csrc[s0] : 0;
    for (int i = s0; i < s1; ++i) {
        int un = (i + 1 < s1) ? csrc[i + 1] : 0;
        const float* hr = hw + (size_t)u * 192 + l;
        float p0 = hr[0], p1 = hr[64], p2 = hr[128];
        sum0 += p0; sum1 += p1; sum2 += p2;
        u = un;
    }
    float ri = rs_in[v];
    const float* sf = stackFT + (size_t)v * 192 + l;
    float v0 = 0.5f * (sf[0]   + sum0 * ri + b_gc[l]);
    float v1 = 0.5f * (sf[64]  + sum1 * ri + b_gc[l + 64]);
    float v2 = 0.5f * (sf[128] + sum2 * ri + b_gc[l + 128]);
    float r = fabsf(v0) + fabsf(v1) + fabsf(v2);
#pragma unroll
    for (int o = 32; o; o >>= 1) r += __shfl_xor(r, o);
    float inv = __fdividef(1.f, fmaxf(r, 1e-12f));
    float* hp = h + (size_t)v * 192 + l;
    hp[0] = v0 * inv; hp[64] = v1 * inv; hp[128] = v2 * inv;
}

// ---------------- GATv2 F=4 (HF=64): 16 lanes/node, one head per lane, fused epilogue
__global__ __launch_bounds__(256)
void gat_edge4(const float* __restrict__ base, int ld,   // fs|fd|res packed, f32
               const float* __restrict__ attn,
               const int* __restrict__ rowstart, const int* __restrict__ csrc,
               float* __restrict__ outp, int n)
{
    int v = blockIdx.x * 16 + (threadIdx.x >> 4);
    int l = threadIdx.x & 15;
    if (v >= n) return;
    float4 at  = *reinterpret_cast<const float4*>(attn + l * 4);
    float4 fdv = *reinterpret_cast<const float4*>(base + (size_t)v * ld + 64 + l * 4);
    float4 acc = make_float4(0.f, 0.f, 0.f, 0.f);
    float dn = 0.f;
    int s0 = rowstart[v], s1 = rowstart[v + 1];
    int u = (s0 < s1) ? csrc[s0] : 0;
    float4 sv = (s0 < s1) ? *reinterpret_cast<const float4*>(base + (size_t)u * ld + l * 4)
                          : make_float4(0.f, 0.f, 0.f, 0.f);
    for (int i = s0; i < s1; ++i) {
        int un = (i + 1 < s1) ? csrc[i + 1] : 0;
        float4 svn = (i + 1 < s1) ? *reinterpret_cast<const float4*>(base + (size_t)un * ld + l * 4)
                                  : make_float4(0.f, 0.f, 0.f, 0.f);
        float ex_, ey, ez, ew;
        ex_ = sv.x + fdv.x; ex_ = (ex_ > 0.f) ? ex_ : 0.2f * ex_;
        ey  = sv.y + fdv.y; ey  = (ey  > 0.f) ? ey  : 0.2f * ey;
        ez  = sv.z + fdv.z; ez  = (ez  > 0.f) ? ez  : 0.2f * ez;
        ew  = sv.w + fdv.w; ew  = (ew  > 0.f) ? ew  : 0.2f * ew;
        float p = ex_ * at.x + ey * at.y + ez * at.z + ew * at.w;
        float ex = __expf(p);
        acc.x += ex * sv.x; acc.y += ex * sv.y; acc.z += ex * sv.z; acc.w += ex * sv.w;
        dn += ex;
        sv = svn; u = un;
    }
    float4 r = *reinterpret_cast<const float4*>(base + (size_t)v * ld + 128 + l * 4);
    float inv = (dn > 0.f) ? __fdividef(1.f, dn) : 0.f;
    float4 o;
    o.x = fmaxf(acc.x * inv + r.x, 0.f);
    o.y = fmaxf(acc.y * inv + r.y, 0.f);
    o.z = fmaxf(acc.z * inv + r.z, 0.f);
    o.w = fmaxf(acc.w * inv + r.w, 0.f);
    *reinterpret_cast<float4*>(outp + (size_t)v * 64 + l * 4) = o;
}

// ---------------- GATv2 F=32 (HF=512): bf16 fs|fd, 128 lanes/node, 8-lane head reduce
__global__ __launch_bounds__(256)
void gat_edge32(const unsigned short* __restrict__ base,   // [n,1024] bf16 fs|fd
                const float* __restrict__ attn,
                const int* __restrict__ rowstart, const int* __restrict__ csrc,
                float* __restrict__ num, float* __restrict__ den, int n)
{
    int v = blockIdx.x * 2 + (threadIdx.x >> 7);
    int l = threadIdx.x & 127;
    if (v >= n) return;
    int head = l >> 3;
    float4 at = *reinterpret_cast<const float4*>(attn + head * 32 + (l & 7) * 4);
    ushort4 fdu = *reinterpret_cast<const ushort4*>(base + (size_t)v * 1024 + 512 + l * 4);
    float4 fdv = make_float4(bf2f(fdu.x), bf2f(fdu.y), bf2f(fdu.z), bf2f(fdu.w));
    float4 acc = make_float4(0.f, 0.f, 0.f, 0.f);
    float dn = 0.f;
    int s0 = rowstart[v], s1 = rowstart[v + 1];
    int u = (s0 < s1) ? csrc[s0] : 0;
    ushort4 su = (s0 < s1) ? *reinterpret_cast<const ushort4*>(base + (size_t)u * 1024 + l * 4)
                           : make_ushort4(0, 0, 0, 0);
    for (int i = s0; i < s1; ++i) {
        int un = (i + 1 < s1) ? csrc[i + 1] : 0;
        ushort4 sun = (i + 1 < s1) ? *reinterpret_cast<const ushort4*>(base + (size_t)un * 1024 + l * 4)
                                   : make_ushort4(0, 0, 0, 0);
        float4 sv = make_float4(bf2f(su.x), bf2f(su.y), bf2f(su.z), bf2f(su.w));
        float ex_, ey, ez, ew;
        ex_ = sv.x + fdv.x; ex_ = (ex_ > 0.f) ? ex_ : 0.2f * ex_;
        ey  = sv.y + fdv.y; ey  = (ey  > 0.f) ? ey  : 0.2f * ey;
        ez  = sv.z + fdv.z; ez  = (ez  > 0.f) ? ez  : 0.2f * ez;
        ew  = sv.w + fdv.w; ew  = (ew  > 0.f) ? ew  : 0.2f * ew;
        float p = ex_ * at.x + ey * at.y + ez * at.z + ew * at.w;
        p += __shfl_xor(p, 1, 8);
        p += __shfl_xor(p, 2, 8);
        p += __shfl_xor(p, 4, 8);
        float ex = __expf(p);
        acc.x += ex * sv.x; acc.y += ex * sv.y; acc.z += ex * sv.z; acc.w += ex * sv.w;
        dn += ex;
        su = sun; u = un;
    }
    *reinterpret_cast<float4*>(num + (size_t)v * 512 + l * 4) = acc;
    if ((l & 7) == 0) den[(size_t)v * 16 + head] = dn;
}

// ---------------- final classifier
__global__ void final_lin(const float* __restrict__ h1, const float* __restrict__ newF,
                          const float* __restrict__ h3, const float* __restrict__ W,
                          const float* __restrict__ bias, float* __restrict__ out, int n)
{
    int gid = blockIdx.x * blockDim.x + threadIdx.x;
    if (gid >= n * 6) return;
    int v = gid / 6, o = gid - v * 6;
    float s = bias[o];
    const float* a = h1 + (size_t)v * 64;
#pragma unroll 8
    for (int r = 0; r < 64; ++r) s += a[r] * W[r * 6 + o];
    const float* b = newF + (size_t)v * 8;
#pragma unroll
    for (int r = 0; r < 8; ++r) s += b[r] * W[(64 + r) * 6 + o];
    const float* c = h3 + (size_t)v * 64;
#pragma unroll 8
    for (int r = 0; r < 64; ++r) s += c[r] * W[(72 + r) * 6 + o];
    out[gid] = s;
}

// ----------------------------------------------------------------------------
extern "C" void kernel_launch(void* const* d_in, const int* in_sizes, int n_in,
                              void* d_out, int out_size, void* d_ws, size_t ws_size,
                              hipStream_t stream)
{
    const float* text   = (const float*)d_in[0];
    const float* audio  = (const float*)d_in[1];
    const float* vision = (const float*)d_in[2];
    const int*   esrc   = (const int*)d_in[3];
    const int*   edst   = (const int*)d_in[4];
    const float* W_audio = (const float*)d_in[5];  const float* b_audio = (const float*)d_in[6];
    const float* W_vision= (const float*)d_in[7];  const float* b_vision= (const float*)d_in[8];
    const float* W_text  = (const float*)d_in[9];  const float* b_text  = (const float*)d_in[10];
    const float* Wih_f = (const float*)d_in[11]; const float* Whh_f = (const float*)d_in[12];
    const float* bih_f = (const float*)d_in[13]; const float* bhh_f = (const float*)d_in[14];
    const float* Wih_b = (const float*)d_in[15]; const float* Whh_b = (const float*)d_in[16];
    const float* bih_b = (const float*)d_in[17]; const float* bhh_b = (const float*)d_in[18];
    const float* W_gc  = (const float*)d_in[19]; const float* b_gc  = (const float*)d_in[20];
    const float* Wsrc2 = (const float*)d_in[21]; const float* bsrc2 = (const float*)d_in[22];
    const float* Wdst2 = (const float*)d_in[23]; const float* bdst2 = (const float*)d_in[24];
    const float* attn2 = (const float*)d_in[25]; const float* Wres2 = (const float*)d_in[26];
    const float* Wsrc0 = (const float*)d_in[27]; const float* bsrc0 = (const float*)d_in[28];
    const float* Wdst0 = (const float*)d_in[29]; const float* bdst0 = (const float*)d_in[30];
    const float* attn0 = (const float*)d_in[31]; const float* Wres0 = (const float*)d_in[32];
    const float* Wsrc1 = (const float*)d_in[33]; const float* bsrc1 = (const float*)d_in[34];
    const float* Wdst1 = (const float*)d_in[35]; const float* bdst1 = (const float*)d_in[36];
    const float* attn1 = (const float*)d_in[37]; const float* Wres1 = (const float*)d_in[38];
    const float* W_lin = (const float*)d_in[39]; const float* b_lin = (const float*)d_in[40];
    float* out = (float*)d_out;

    const int n = in_sizes[0] / 1024;   // 12000
    const int E = in_sizes[3];          // 192000
    const int B = n / 120;              // 100

    // ---- workspace carve (256B aligned) — layout unchanged
    char* p = (char*)d_ws;
    auto alloc_f = [&](size_t cnt) { float* r = (float*)p; p += ((cnt * 4 + 255) / 256) * 256; return r; };
    auto alloc_i = [&](size_t cnt) { int* r = (int*)p; p += ((cnt * 4 + 255) / 256) * 256; return r; };
    float* stackFT = alloc_f((size_t)n * 192);
    float* hbuf    = alloc_f((size_t)n * 192);
    float* xWf     = alloc_f((size_t)n * 16);
    float* xWb     = alloc_f((size_t)n * 16);
    float* newF    = alloc_f((size_t)n * 8);
    float* big0    = alloc_f((size_t)n * 512);   // gat0: bf16 fs|fd [n,1024] fits in half
    float* big1    = alloc_f((size_t)n * 512);   // (unused this round)
    float* big2    = alloc_f((size_t)n * 512);   // num0 -> h0 f32 [n,512]
    float* den     = alloc_f((size_t)n * 16);
    float* h3      = alloc_f((size_t)n * 64);
    float* h1s     = alloc_f((size_t)n * 64);    // doubles as packed-weight scratch until gat1 edge
    float* rs_out  = alloc_f(n);
    float* rs_in   = alloc_f(n);
    int* zero_base = alloc_i((size_t)3 * n);
    int* degout = zero_base;
    int* degin  = zero_base + n;
    int* cursor = zero_base + 2 * n;
    int* rowstart = alloc_i((size_t)n + 1);
    int* perm     = alloc_i((size_t)E);
    if ((size_t)(p - (char*)d_ws) > ws_size) return;
    (void)big1;

    float* pw = h1s;
    float* pb = h1s + 200704;

    // ---- graph preprocessing
    hipMemsetAsync(zero_base, 0, (size_t)3 * n * 4, stream);
    deg_kernel<<<(E + 255) / 256, 256, 0, stream>>>(esrc, edst, degout, degin, E);
    scan_kernel<<<1, 1024, 0, stream>>>(degin, rowstart, n);
    perm_kernel<<<(E + 255) / 256, 256, 0, stream>>>(edst, rowstart, cursor, perm, E);
    gather_src_kernel<<<(E + 255) / 256, 256, 0, stream>>>(esrc, perm, E);
    rs_kernel<<<(n + 255) / 256, 256, 0, stream>>>(degout, degin, rs_out, rs_in, n);
    const int* csrc = perm;

    auto g64 = [&](const float* A, const float* Bm, const float* bias, const float* rsc,
                   float* Cp, const float* fden, int M, int Nb, int K, int ldc) {
        dim3 grid((M + 63) / 64, Nb / 64);
        gemm_direct<false, 1><<<grid, 256, 0, stream>>>(A, Bm, bias, rsc, Cp, fden, M, Nb, K, ldc, 0);
    };
    auto g128bf = [&](const float* A, const float* Bm, const float* bias,
                      unsigned short* Cp, int M, int Nb, int K, int ldc) {
        dim3 grid((M + 127) / 128, Nb / 64);
        gemm_direct<true, 2><<<grid, 256, 0, stream>>>(A, Bm, bias, nullptr, Cp, nullptr, M, Nb, K, ldc, 0);
    };

    // ---- modality encoders -> stackFT [n,192] (bf16x3 MFMA, A-direct, ~f32 accuracy)
    {
        dim3 grid(n / 32, 1, 3);
        enc_mfma2<<<grid, 256, 0, stream>>>(text, audio, vision, W_text, W_audio, W_vision,
                                            b_text, b_audio, b_vision, stackFT, n);
    }

    // ---- BiLSTM
    lstm_pre<<<(n * 32 + 255) / 256, 256, 0, stream>>>(stackFT, Wih_f, Wih_b,
                                                       bih_f, bhh_f, bih_b, bhh_b, xWf, xWb, n);
    lstm_seq2<<<(2 * B + 3) / 4, 64, 0, stream>>>(xWf, xWb, Whh_f, Whh_b, newF, B);

    // ---- GraphConv imputation + L1 norm -> hbuf
    g64(stackFT, W_gc, nullptr, rs_out, big0, nullptr, n, 192, 192, 192);
    gc_combine2<<<(n + 3) / 4, 256, 0, stream>>>(stackFT, big0, rowstart, csrc, rs_in, b_gc, hbuf, n);

    // ---- gat2: packed src|dst|res GEMM -> stackFT [n,192], fused edge -> h3
    pack3_kernel<<<(192 * 192 + 255) / 256, 256, 0, stream>>>(Wsrc2, Wdst2, Wres2, bsrc2, bdst2, pw, pb, 192, 64);
    g64(hbuf, pw, pb, nullptr, stackFT, nullptr, n, 192, 192, 192);
    gat_edge4<<<(n + 15) / 16, 256, 0, stream>>>(stackFT, 192, attn2, rowstart, csrc, h3, n);

    // ---- gat0: packed src|dst GEMM -> big0 bf16 [n,1024]; edge -> big2; res GEMM w/ fused finalize
    pack2_kernel<<<(192 * 1024 + 255) / 256, 256, 0, stream>>>(Wsrc0, Wdst0, bsrc0, bdst0, pw, pb, 192, 512);
    g128bf(hbuf, pw, pb, (unsigned short*)big0, n, 1024, 192, 1024);
    gat_edge32<<<(n + 1) / 2, 256, 0, stream>>>((const unsigned short*)big0, attn0, rowstart, csrc, big2, den, n);
    g64(hbuf, Wres0, nullptr, nullptr, big2, den, n, 512, 192, 512);   // big2 = relu(big2/den + res)

    // ---- gat1: packed src|dst|res GEMM -> big0 f32 [n,192], fused edge -> h1s
    pack3_kernel<<<(512 * 192 + 255) / 256, 256, 0, stream>>>(Wsrc1, Wdst1, Wres1, bsrc1, bdst1, pw, pb, 512, 64);
    g64(big2, pw, pb, nullptr, big0, nullptr, n, 192, 512, 192);
    gat_edge4<<<(n + 15) / 16, 256, 0, stream>>>(big0, 192, attn1, rowstart, csrc, h1s, n);

    // ---- final classifier
    final_lin<<<(n * 6 + 255) / 256, 256, 0, stream>>>(h1s, newF, h3, W_lin, b_lin, out, n);
}

// Round 6
// 397.426 us; speedup vs baseline: 1.4658x; 1.4658x over previous
//
#include <hip/hip_runtime.h>

typedef __attribute__((ext_vector_type(8))) short short8;
typedef __attribute__((ext_vector_type(4))) float f32x4;

__device__ __forceinline__ unsigned short f2bf(float f) {
    unsigned u = __float_as_uint(f);
    u += 0x7FFFu + ((u >> 16) & 1u);
    return (unsigned short)(u >> 16);
}
__device__ __forceinline__ float bf2f(unsigned short h) {
    return __uint_as_float((unsigned)h << 16);
}

// =====================================================================
// gemm_v6: C[M,Nb] = A[M,K](bf16)@B[K,Nb](f32) (+bias)(*rowscale)
// A staged coalesced to linear LDS [BM][32] bf16 (bank-floor reads+writes).
// B staged column-per-lane (coalesced 256B row reads, bank-floor writes).
// OUTMODE: 0 = f32 out, 1 = bf16 out, 2 = bf16 out with fused GAT finalize
//          (out = relu(fin_num/fin_den + gemm))
template<int MF, int OUTMODE>
__global__ __launch_bounds__(256)
void gemm_v6(const unsigned short* __restrict__ A, const float* __restrict__ B,
             const float* __restrict__ bias, const float* __restrict__ rowscale,
             void* __restrict__ Cv, const float* __restrict__ fin_num,
             const float* __restrict__ fin_den,
             int M, int Nb, int K, int ldc)
{
    __shared__ alignas(16) unsigned short As[MF * 64 * 32];
    __shared__ alignas(16) unsigned short Bs[4 * 64 * 8];
    const int t = threadIdx.x;
    const int w = t >> 6, l = t & 63;
    const int r16 = l & 15, kg = l >> 4;
    const int row0 = blockIdx.x * (64 * MF);
    const int col0 = blockIdx.y * 64;
    const int bcol = t & 63, bkg = t >> 6;   // B staging: lane owns col bcol, k-group bkg

    f32x4 acc[MF][4] = {};
    const short8 z8 = {0, 0, 0, 0, 0, 0, 0, 0};

    for (int k0 = 0; k0 < K; k0 += 32) {
        // ---- stage A: MF*64 rows x 32 k bf16, coalesced (16B per lane, 4 lanes/row)
#pragma unroll
        for (int it = 0; it < MF; ++it) {
            int idx = it * 256 + t;
            int row = idx >> 2, ch = idx & 3;
            int gm = row0 + row;
            short8 v = z8;
            if (gm < M) v = *reinterpret_cast<const short8*>(A + (size_t)gm * K + k0 + ch * 8);
            *reinterpret_cast<short8*>(&As[row * 32 + ch * 8]) = v;
        }
        // ---- stage B: 32k x 64col; lane reads 8 k-values of its column (coalesced by wave)
        {
            const float* bp = B + (size_t)(k0 + bkg * 8) * Nb + col0 + bcol;
            short8 hv;
#pragma unroll
            for (int j = 0; j < 8; ++j) hv[j] = (short)f2bf(bp[(size_t)j * Nb]);
            *reinterpret_cast<short8*>(&Bs[bkg * 512 + bcol * 8]) = hv;
        }
        __syncthreads();
        short8 af[MF];
#pragma unroll
        for (int mi = 0; mi < MF; ++mi)
            af[mi] = *reinterpret_cast<const short8*>(&As[((w * MF + mi) * 16 + r16) * 32 + kg * 8]);
#pragma unroll
        for (int ni = 0; ni < 4; ++ni) {
            short8 bf = *reinterpret_cast<const short8*>(&Bs[kg * 512 + (ni * 16 + r16) * 8]);
#pragma unroll
            for (int mi = 0; mi < MF; ++mi)
                acc[mi][ni] = __builtin_amdgcn_mfma_f32_16x16x32_bf16(af[mi], bf, acc[mi][ni], 0, 0, 0);
        }
        __syncthreads();
    }
#pragma unroll
    for (int mi = 0; mi < MF; ++mi)
#pragma unroll
        for (int ni = 0; ni < 4; ++ni) {
            int col = col0 + ni * 16 + r16;
            float bv = bias ? bias[col] : 0.f;
#pragma unroll
            for (int r = 0; r < 4; ++r) {
                int gm = row0 + (w * MF + mi) * 16 + kg * 4 + r;
                if (gm < M) {
                    float val = acc[mi][ni][r] + bv;
                    if (rowscale) val *= rowscale[gm];
                    size_t idx = (size_t)gm * ldc + col;
                    if (OUTMODE == 0) {
                        ((float*)Cv)[idx] = val;
                    } else if (OUTMODE == 1) {
                        ((unsigned short*)Cv)[idx] = f2bf(val);
                    } else {
                        float d = fin_den[(size_t)gm * 16 + (col >> 5)];
                        float inv = (d > 0.f) ? __fdividef(1.f, d) : 0.f;
                        float o = fmaxf(fin_num[idx] * inv + val, 0.f);
                        ((unsigned short*)Cv)[idx] = f2bf(o);
                    }
                }
            }
        }
}

// =====================================================================
// encoder: bf16x3 split precision (x_hi*W_hi + x_hi*W_lo + x_lo*W_hi), f32 in.
// BM=32, A staged coalesced hi/lo; B (weights, 64 cols) staged column-per-lane hi/lo.
// Dual epilogue: stackFT f32 + stackBF bf16.
__global__ __launch_bounds__(256)
void enc_mfma3(const float* __restrict__ text, const float* __restrict__ audio, const float* __restrict__ vision,
               const float* __restrict__ Wt, const float* __restrict__ Wa, const float* __restrict__ Wv,
               const float* __restrict__ bt, const float* __restrict__ ba, const float* __restrict__ bv,
               float* __restrict__ Cf, unsigned short* __restrict__ Cb, int M)
{
    __shared__ alignas(16) unsigned short Ah[32 * 32], Ao[32 * 32];
    __shared__ alignas(16) unsigned short Bh[4 * 64 * 8], Bo[4 * 64 * 8];
    const int z = blockIdx.z;
    const float* A  = (z == 0) ? text : (z == 1) ? audio : vision;
    const float* W  = (z == 0) ? Wt   : (z == 1) ? Wa    : Wv;
    const float* bb = (z == 0) ? bt   : (z == 1) ? ba    : bv;
    const int K = (z == 1) ? 512 : 1024;

    const int t = threadIdx.x;
    const int w = t >> 6, l = t & 63;
    const int r16 = l & 15, kg = l >> 4;
    const int row0 = blockIdx.x * 32;
    const int mi = w & 1;             // m-frag
    const int ncol0 = (w >> 1) * 32;  // 2 n-frags per wave
    const int arow = t >> 3, ac8 = t & 7;        // A staging coords
    const int bcol = t & 63, bkg = t >> 6;       // B staging coords

    f32x4 acc[2] = {};
    for (int k0 = 0; k0 < K; k0 += 32) {
        // stage A tile [32][32] f32 -> hi/lo bf16 (coalesced: 8 lanes x 16B per row)
        {
            float4 av = *reinterpret_cast<const float4*>(A + (size_t)(row0 + arow) * K + k0 + ac8 * 4);
            float vv[4] = {av.x, av.y, av.z, av.w};
            ushort4 hi, lo;
            unsigned short* hp = (unsigned short*)&hi;
            unsigned short* lp = (unsigned short*)&lo;
#pragma unroll
            for (int j = 0; j < 4; ++j) {
                unsigned short h = f2bf(vv[j]);
                hp[j] = h;
                lp[j] = f2bf(vv[j] - bf2f(h));
            }
            *reinterpret_cast<ushort4*>(&Ah[arow * 32 + ac8 * 4]) = hi;
            *reinterpret_cast<ushort4*>(&Ao[arow * 32 + ac8 * 4]) = lo;
        }
        // stage B: lane owns col, 8 coalesced k-row reads, hi/lo
        {
            const float* bp = W + (size_t)(k0 + bkg * 8) * 64 + bcol;
            short8 hv, lv;
#pragma unroll
            for (int j = 0; j < 8; ++j) {
                float x = bp[(size_t)j * 64];
                unsigned short h = f2bf(x);
                hv[j] = (short)h;
                lv[j] = (short)f2bf(x - bf2f(h));
            }
            *reinterpret_cast<short8*>(&Bh[bkg * 512 + bcol * 8]) = hv;
            *reinterpret_cast<short8*>(&Bo[bkg * 512 + bcol * 8]) = lv;
        }
        __syncthreads();
        short8 ah = *reinterpret_cast<const short8*>(&Ah[(mi * 16 + r16) * 32 + kg * 8]);
        short8 ao = *reinterpret_cast<const short8*>(&Ao[(mi * 16 + r16) * 32 + kg * 8]);
#pragma unroll
        for (int ni = 0; ni < 2; ++ni) {
            int ci = kg * 512 + (ncol0 + ni * 16 + r16) * 8;
            short8 bhv = *reinterpret_cast<const short8*>(&Bh[ci]);
            short8 bov = *reinterpret_cast<const short8*>(&Bo[ci]);
            acc[ni] = __builtin_amdgcn_mfma_f32_16x16x32_bf16(ah, bhv, acc[ni], 0, 0, 0);
            acc[ni] = __builtin_amdgcn_mfma_f32_16x16x32_bf16(ah, bov, acc[ni], 0, 0, 0);
            acc[ni] = __builtin_amdgcn_mfma_f32_16x16x32_bf16(ao, bhv, acc[ni], 0, 0, 0);
        }
        __syncthreads();
    }
#pragma unroll
    for (int ni = 0; ni < 2; ++ni) {
        int col = ncol0 + ni * 16 + r16;
        float bvv = bb[col];
#pragma unroll
        for (int r = 0; r < 4; ++r) {
            int gr = row0 + mi * 16 + kg * 4 + r;
            if (gr < M) {
                float val = acc[ni][r] + bvv;
                size_t idx = (size_t)gr * 192 + z * 64 + col;
                Cf[idx] = val;
                Cb[idx] = f2bf(val);
            }
        }
    }
}

// ---------------- weight packing
__global__ void pack3_kernel(const float* __restrict__ W0, const float* __restrict__ W1, const float* __restrict__ W2,
                             const float* __restrict__ b0, const float* __restrict__ b1,
                             float* __restrict__ Wp, float* __restrict__ bp, int K, int O)
{
    int gid = blockIdx.x * blockDim.x + threadIdx.x;
    int O3 = 3 * O;
    if (gid < O3) bp[gid] = (gid < O) ? b0[gid] : (gid < 2 * O) ? b1[gid - O] : 0.f;
    if (gid >= K * O3) return;
    int k = gid / O3, c = gid - k * O3;
    float v = (c < O) ? W0[k * O + c] : (c < 2 * O) ? W1[k * O + c - O] : W2[k * O + c - 2 * O];
    Wp[gid] = v;
}

__global__ void pack2_kernel(const float* __restrict__ W0, const float* __restrict__ W1,
                             const float* __restrict__ b0, const float* __restrict__ b1,
                             float* __restrict__ Wp, float* __restrict__ bp, int K, int O)
{
    int gid = blockIdx.x * blockDim.x + threadIdx.x;
    int O2 = 2 * O;
    if (gid < O2) bp[gid] = (gid < O) ? b0[gid] : b1[gid - O];
    if (gid >= K * O2) return;
    int k = gid / O2, c = gid - k * O2;
    Wp[gid] = (c < O) ? W0[k * O + c] : W1[k * O + c - O];
}

// ---------------- graph preprocessing
__global__ void deg_kernel(const int* __restrict__ src, const int* __restrict__ dst,
                           int* degout, int* degin, int E)
{
    int e = blockIdx.x * blockDim.x + threadIdx.x;
    if (e < E) {
        atomicAdd(&degout[src[e]], 1);
        atomicAdd(&degin[dst[e]], 1);
    }
}

__global__ __launch_bounds__(1024)
void scan_kernel(const int* __restrict__ degin, int* __restrict__ rowstart, int n)
{
    __shared__ int part[1024];
    int t = threadIdx.x;
    int chunk = (n + 1023) / 1024;
    int s = 0;
    for (int i = 0; i < chunk; ++i) {
        int idx = t * chunk + i;
        if (idx < n) s += degin[idx];
    }
    part[t] = s;
    __syncthreads();
    for (int o = 1; o < 1024; o <<= 1) {
        int v = (t >= o) ? part[t - o] : 0;
        __syncthreads();
        part[t] += v;
        __syncthreads();
    }
    int run = (t > 0) ? part[t - 1] : 0;
    for (int i = 0; i < chunk; ++i) {
        int idx = t * chunk + i;
        if (idx < n) { rowstart[idx] = run; run += degin[idx]; }
    }
    if (t == 1023) rowstart[n] = part[1023];
}

__global__ void perm_kernel(const int* __restrict__ dst, const int* __restrict__ rowstart,
                            int* cursor, int* __restrict__ perm, int E)
{
    int e = blockIdx.x * blockDim.x + threadIdx.x;
    if (e < E) {
        int v = dst[e];
        int p = atomicAdd(&cursor[v], 1);
        perm[rowstart[v] + p] = e;
    }
}

__global__ void gather_src_kernel(const int* __restrict__ esrc, int* perm, int E)
{
    int i = blockIdx.x * blockDim.x + threadIdx.x;
    if (i < E) perm[i] = esrc[perm[i]];
}

__global__ void rs_kernel(const int* degout, const int* degin, float* rso, float* rsi, int n)
{
    int i = blockIdx.x * blockDim.x + threadIdx.x;
    if (i < n) {
        rso[i] = rsqrtf((float)max(degout[i], 1));
        rsi[i] = rsqrtf((float)max(degin[i], 1));
    }
}

// ---------------- LSTM
__global__ void lstm_pre(const float* __restrict__ x, const float* __restrict__ Wf,
                         const float* __restrict__ Wb,
                         const float* bf1, const float* bf2, const float* bb1, const float* bb2,
                         float* __restrict__ xWf, float* __restrict__ xWb, int n)
{
    int gid = blockIdx.x * blockDim.x + threadIdx.x;
    if (gid >= n * 32) return;
    int nn = gid >> 5, r = gid & 31, d = r >> 4, j = r & 15;
    const float* W = (d ? Wb : Wf) + j * 192;
    const float* xr = x + (size_t)nn * 192;
    float s = 0.f;
#pragma unroll 4
    for (int k = 0; k < 192; k += 4) {
        float4 xv = *reinterpret_cast<const float4*>(xr + k);
        float4 wv = *reinterpret_cast<const float4*>(W + k);
        s += xv.x * wv.x + xv.y * wv.y + xv.z * wv.z + xv.w * wv.w;
    }
    s += d ? (bb1[j] + bb2[j]) : (bf1[j] + bf2[j]);
    int b = nn / 120, tt = nn - b * 120;
    (d ? xWb : xWf)[((size_t)b * 16 + j) * 120 + tt] = s;
}

__device__ __forceinline__ float fsigm(float x) { return __fdividef(1.f, 1.f + __expf(-x)); }
__device__ __forceinline__ float ftanh(float x) { return 1.f - __fdividef(2.f, __expf(2.f * x) + 1.f); }

template<int DIR>
__device__ void lstm_chain(const float* __restrict__ xw, const float* __restrict__ whh,
                           float* __restrict__ newF, int b)
{
    int j = threadIdx.x & 15;
    int k = j & 3;
    float4 w = *reinterpret_cast<const float4*>(whh + j * 4);
    const float* xp = xw + ((size_t)b * 16 + j) * 120;
    float h0 = 0.f, h1 = 0.f, h2 = 0.f, h3 = 0.f, cst = 0.f;
    int tb0 = DIR ? 108 : 0;
    float4 a0 = *reinterpret_cast<const float4*>(xp + tb0);
    float4 a1 = *reinterpret_cast<const float4*>(xp + tb0 + 4);
    float4 a2 = *reinterpret_cast<const float4*>(xp + tb0 + 8);
    for (int ch = 0; ch < 10; ++ch) {
        float4 b0 = a0, b1 = a1, b2 = a2;
        if (ch < 9) {
            int nt = DIR ? (96 - ch * 12) : (12 + ch * 12);
            b0 = *reinterpret_cast<const float4*>(xp + nt);
            b1 = *reinterpret_cast<const float4*>(xp + nt + 4);
            b2 = *reinterpret_cast<const float4*>(xp + nt + 8);
        }
        float zz[12] = {a0.x, a0.y, a0.z, a0.w, a1.x, a1.y, a1.z, a1.w, a2.x, a2.y, a2.z, a2.w};
        int tbase = DIR ? (108 - ch * 12) : (ch * 12);
#pragma unroll
        for (int ii = 0; ii < 12; ++ii) {
            int idx = DIR ? (11 - ii) : ii;
            float z = zz[idx] + ((w.x * h0 + w.y * h1) + (w.z * h2 + w.w * h3));
            float zi = __shfl(z, k, 16);
            float zf = __shfl(z, k + 4, 16);
            float zg = __shfl(z, k + 8, 16);
            float zo = __shfl(z, k + 12, 16);
            float ig = fsigm(zi), fg = fsigm(zf), gg = ftanh(zg), og = fsigm(zo);
            cst = fg * cst + ig * gg;
            float hn = og * ftanh(cst);
            h0 = __shfl(hn, 0, 16); h1 = __shfl(hn, 1, 16);
            h2 = __shfl(hn, 2, 16); h3 = __shfl(hn, 3, 16);
            if (j < 4) newF[((size_t)b * 120 + tbase + idx) * 8 + DIR * 4 + j] = hn;
        }
        a0 = b0; a1 = b1; a2 = b2;
    }
}

__global__ __launch_bounds__(64)
void lstm_seq2(const float* __restrict__ xWf, const float* __restrict__ xWb,
               const float* __restrict__ Whhf, const float* __restrict__ Whhb,
               float* __restrict__ newF, int B)
{
    int sub = threadIdx.x >> 4;
    int chain = blockIdx.x * 4 + sub;
    if (chain >= 2 * B) return;
    int d = chain / B;
    int b = chain - d * B;
    if (d == 0) lstm_chain<0>(xWf, Whhf, newF, b);
    else        lstm_chain<1>(xWb, Whhb, newF, b);
}

// ---------------- GraphConv combine + L1 norm: one wave per node, writes bf16 h
__global__ __launch_bounds__(256)
void gc_combine3(const float* __restrict__ stackFT, const float* __restrict__ hw,
                 const int* __restrict__ rowstart, const int* __restrict__ csrc,
                 const float* __restrict__ rs_in,
                 const float* __restrict__ b_gc, unsigned short* __restrict__ hB, int n)
{
    int v = blockIdx.x * 4 + (threadIdx.x >> 6);
    int l = threadIdx.x & 63;
    if (v >= n) return;
    int s0 = rowstart[v], s1 = rowstart[v + 1];
    float sum0 = 0.f, sum1 = 0.f, sum2 = 0.f;
    int u = (s0 < s1) ? csrc[s0] : 0;
    for (int i = s0; i < s1; ++i) {
        int un = (i + 1 < s1) ? csrc[i + 1] : 0;
        const float* hr = hw + (size_t)u * 192 + l;
        float p0 = hr[0], p1 = hr[64], p2 = hr[128];
        sum0 += p0; sum1 += p1; sum2 += p2;
        u = un;
    }
    float ri = rs_in[v];
    const float* sf = stackFT + (size_t)v * 192 + l;
    float v0 = 0.5f * (sf[0]   + sum0 * ri + b_gc[l]);
    float v1 = 0.5f * (sf[64]  + sum1 * ri + b_gc[l + 64]);
    float v2 = 0.5f * (sf[128] + sum2 * ri + b_gc[l + 128]);
    float r = fabsf(v0) + fabsf(v1) + fabsf(v2);
#pragma unroll
    for (int o = 32; o; o >>= 1) r += __shfl_xor(r, o);
    float inv = __fdividef(1.f, fmaxf(r, 1e-12f));
    unsigned short* hp = hB + (size_t)v * 192 + l;
    hp[0]   = f2bf(v0 * inv);
    hp[64]  = f2bf(v1 * inv);
    hp[128] = f2bf(v2 * inv);
}

// ---------------- GATv2 F=4 (HF=64): 16 lanes/node, one head per lane, fused epilogue
__global__ __launch_bounds__(256)
void gat_edge4(const float* __restrict__ base, int ld,   // fs|fd|res packed, f32
               const float* __restrict__ attn,
               const int* __restrict__ rowstart, const int* __restrict__ csrc,
               float* __restrict__ outp, int n)
{
    int v = blockIdx.x * 16 + (threadIdx.x >> 4);
    int l = threadIdx.x & 15;
    if (v >= n) return;
    float4 at  = *reinterpret_cast<const float4*>(attn + l * 4);
    float4 fdv = *reinterpret_cast<const float4*>(base + (size_t)v * ld + 64 + l * 4);
    float4 acc = make_float4(0.f, 0.f, 0.f, 0.f);
    float dn = 0.f;
    int s0 = rowstart[v], s1 = rowstart[v + 1];
    int u = (s0 < s1) ? csrc[s0] : 0;
    float4 sv = (s0 < s1) ? *reinterpret_cast<const float4*>(base + (size_t)u * ld + l * 4)
                          : make_float4(0.f, 0.f, 0.f, 0.f);
    for (int i = s0; i < s1; ++i) {
        int un = (i + 1 < s1) ? csrc[i + 1] : 0;
        float4 svn = (i + 1 < s1) ? *reinterpret_cast<const float4*>(base + (size_t)un * ld + l * 4)
                                  : make_float4(0.f, 0.f, 0.f, 0.f);
        float ex_, ey, ez, ew;
        ex_ = sv.x + fdv.x; ex_ = (ex_ > 0.f) ? ex_ : 0.2f * ex_;
        ey  = sv.y + fdv.y; ey  = (ey  > 0.f) ? ey  : 0.2f * ey;
        ez  = sv.z + fdv.z; ez  = (ez  > 0.f) ? ez  : 0.2f * ez;
        ew  = sv.w + fdv.w; ew  = (ew  > 0.f) ? ew  : 0.2f * ew;
        float p = ex_ * at.x + ey * at.y + ez * at.z + ew * at.w;
        float ex = __expf(p);
        acc.x += ex * sv.x; acc.y += ex * sv.y; acc.z += ex * sv.z; acc.w += ex * sv.w;
        dn += ex;
        sv = svn; u = un;
    }
    float4 r = *reinterpret_cast<const float4*>(base + (size_t)v * ld + 128 + l * 4);
    float inv = (dn > 0.f) ? __fdividef(1.f, dn) : 0.f;
    float4 o;
    o.x = fmaxf(acc.x * inv + r.x, 0.f);
    o.y = fmaxf(acc.y * inv + r.y, 0.f);
    o.z = fmaxf(acc.z * inv + r.z, 0.f);
    o.w = fmaxf(acc.w * inv + r.w, 0.f);
    *reinterpret_cast<float4*>(outp + (size_t)v * 64 + l * 4) = o;
}

// ---------------- GATv2 F=32 (HF=512): bf16 fs|fd, 128 lanes/node, 8-lane head reduce
__global__ __launch_bounds__(256)
void gat_edge32(const unsigned short* __restrict__ base,   // [n,1024] bf16 fs|fd
                const float* __restrict__ attn,
                const int* __restrict__ rowstart, const int* __restrict__ csrc,
                float* __restrict__ num, float* __restrict__ den, int n)
{
    int v = blockIdx.x * 2 + (threadIdx.x >> 7);
    int l = threadIdx.x & 127;
    if (v >= n) return;
    int head = l >> 3;
    float4 at = *reinterpret_cast<const float4*>(attn + head * 32 + (l & 7) * 4);
    ushort4 fdu = *reinterpret_cast<const ushort4*>(base + (size_t)v * 1024 + 512 + l * 4);
    float4 fdv = make_float4(bf2f(fdu.x), bf2f(fdu.y), bf2f(fdu.z), bf2f(fdu.w));
    float4 acc = make_float4(0.f, 0.f, 0.f, 0.f);
    float dn = 0.f;
    int s0 = rowstart[v], s1 = rowstart[v + 1];
    int u = (s0 < s1) ? csrc[s0] : 0;
    ushort4 su = (s0 < s1) ? *reinterpret_cast<const ushort4*>(base + (size_t)u * 1024 + l * 4)
                           : make_ushort4(0, 0, 0, 0);
    for (int i = s0; i < s1; ++i) {
        int un = (i + 1 < s1) ? csrc[i + 1] : 0;
        ushort4 sun = (i + 1 < s1) ? *reinterpret_cast<const ushort4*>(base + (size_t)un * 1024 + l * 4)
                                   : make_ushort4(0, 0, 0, 0);
        float4 sv = make_float4(bf2f(su.x), bf2f(su.y), bf2f(su.z), bf2f(su.w));
        float ex_, ey, ez, ew;
        ex_ = sv.x + fdv.x; ex_ = (ex_ > 0.f) ? ex_ : 0.2f * ex_;
        ey  = sv.y + fdv.y; ey  = (ey  > 0.f) ? ey  : 0.2f * ey;
        ez  = sv.z + fdv.z; ez  = (ez  > 0.f) ? ez  : 0.2f * ez;
        ew  = sv.w + fdv.w; ew  = (ew  > 0.f) ? ew  : 0.2f * ew;
        float p = ex_ * at.x + ey * at.y + ez * at.z + ew * at.w;
        p += __shfl_xor(p, 1, 8);
        p += __shfl_xor(p, 2, 8);
        p += __shfl_xor(p, 4, 8);
        float ex = __expf(p);
        acc.x += ex * sv.x; acc.y += ex * sv.y; acc.z += ex * sv.z; acc.w += ex * sv.w;
        dn += ex;
        su = sun; u = un;
    }
    *reinterpret_cast<float4*>(num + (size_t)v * 512 + l * 4) = acc;
    if ((l & 7) == 0) den[(size_t)v * 16 + head] = dn;
}

// ---------------- final classifier
__global__ void final_lin(const float* __restrict__ h1, const float* __restrict__ newF,
                          const float* __restrict__ h3, const float* __restrict__ W,
                          const float* __restrict__ bias, float* __restrict__ out, int n)
{
    int gid = blockIdx.x * blockDim.x + threadIdx.x;
    if (gid >= n * 6) return;
    int v = gid / 6, o = gid - v * 6;
    float s = bias[o];
    const float* a = h1 + (size_t)v * 64;
#pragma unroll 8
    for (int r = 0; r < 64; ++r) s += a[r] * W[r * 6 + o];
    const float* b = newF + (size_t)v * 8;
#pragma unroll
    for (int r = 0; r < 8; ++r) s += b[r] * W[(64 + r) * 6 + o];
    const float* c = h3 + (size_t)v * 64;
#pragma unroll 8
    for (int r = 0; r < 64; ++r) s += c[r] * W[(72 + r) * 6 + o];
    out[gid] = s;
}

// ----------------------------------------------------------------------------
extern "C" void kernel_launch(void* const* d_in, const int* in_sizes, int n_in,
                              void* d_out, int out_size, void* d_ws, size_t ws_size,
                              hipStream_t stream)
{
    const float* text   = (const float*)d_in[0];
    const float* audio  = (const float*)d_in[1];
    const float* vision = (const float*)d_in[2];
    const int*   esrc   = (const int*)d_in[3];
    const int*   edst   = (const int*)d_in[4];
    const float* W_audio = (const float*)d_in[5];  const float* b_audio = (const float*)d_in[6];
    const float* W_vision= (const float*)d_in[7];  const float* b_vision= (const float*)d_in[8];
    const float* W_text  = (const float*)d_in[9];  const float* b_text  = (const float*)d_in[10];
    const float* Wih_f = (const float*)d_in[11]; const float* Whh_f = (const float*)d_in[12];
    const float* bih_f = (const float*)d_in[13]; const float* bhh_f = (const float*)d_in[14];
    const float* Wih_b = (const float*)d_in[15]; const float* Whh_b = (const float*)d_in[16];
    const float* bih_b = (const float*)d_in[17]; const float* bhh_b = (const float*)d_in[18];
    const float* W_gc  = (const float*)d_in[19]; const float* b_gc  = (const float*)d_in[20];
    const float* Wsrc2 = (const float*)d_in[21]; const float* bsrc2 = (const float*)d_in[22];
    const float* Wdst2 = (const float*)d_in[23]; const float* bdst2 = (const float*)d_in[24];
    const float* attn2 = (const float*)d_in[25]; const float* Wres2 = (const float*)d_in[26];
    const float* Wsrc0 = (const float*)d_in[27]; const float* bsrc0 = (const float*)d_in[28];
    const float* Wdst0 = (const float*)d_in[29]; const float* bdst0 = (const float*)d_in[30];
    const float* attn0 = (const float*)d_in[31]; const float* Wres0 = (const float*)d_in[32];
    const float* Wsrc1 = (const float*)d_in[33]; const float* bsrc1 = (const float*)d_in[34];
    const float* Wdst1 = (const float*)d_in[35]; const float* bdst1 = (const float*)d_in[36];
    const float* attn1 = (const float*)d_in[37]; const float* Wres1 = (const float*)d_in[38];
    const float* W_lin = (const float*)d_in[39]; const float* b_lin = (const float*)d_in[40];
    float* out = (float*)d_out;

    const int n = in_sizes[0] / 1024;   // 12000
    const int E = in_sizes[3];          // 192000
    const int B = n / 120;              // 100

    // ---- workspace carve (256B aligned)
    char* p = (char*)d_ws;
    auto alloc_f = [&](size_t cnt) { float* r = (float*)p; p += ((cnt * 4 + 255) / 256) * 256; return r; };
    auto alloc_h = [&](size_t cnt) { unsigned short* r = (unsigned short*)p; p += ((cnt * 2 + 255) / 256) * 256; return r; };
    auto alloc_i = [&](size_t cnt) { int* r = (int*)p; p += ((cnt * 4 + 255) / 256) * 256; return r; };
    float*          stackFT = alloc_f((size_t)n * 192);  // f32 (lstm, gc residual)
    unsigned short* stackBF = alloc_h((size_t)n * 192);  // bf16 copy (gc GEMM A)
    unsigned short* hbufBF  = alloc_h((size_t)n * 192);  // bf16 h (gat2/gat0/res0 GEMM A)
    float* xWf     = alloc_f((size_t)n * 16);
    float* xWb     = alloc_f((size_t)n * 16);
    float* newF    = alloc_f((size_t)n * 8);
    float* big0    = alloc_f((size_t)n * 512);   // gc out f32[n,192] -> gat2 out f32[n,192] -> gat0 out bf16[n,1024] -> gat1 out f32[n,192]
    float* big1    = alloc_f((size_t)n * 512);   // res0-fused out bf16 [n,512] (first half)
    float* big2    = alloc_f((size_t)n * 512);   // gat0 num f32 [n,512]
    float* den     = alloc_f((size_t)n * 16);
    float* h3      = alloc_f((size_t)n * 64);
    float* h1s     = alloc_f((size_t)n * 64);    // doubles as packed-weight scratch until gat1 edge
    float* rs_out  = alloc_f(n);
    float* rs_in   = alloc_f(n);
    int* zero_base = alloc_i((size_t)3 * n);
    int* degout = zero_base;
    int* degin  = zero_base + n;
    int* cursor = zero_base + 2 * n;
    int* rowstart = alloc_i((size_t)n + 1);
    int* perm     = alloc_i((size_t)E);
    if ((size_t)(p - (char*)d_ws) > ws_size) return;

    float* pw = h1s;
    float* pb = h1s + 200704;

    // ---- graph preprocessing
    hipMemsetAsync(zero_base, 0, (size_t)3 * n * 4, stream);
    deg_kernel<<<(E + 255) / 256, 256, 0, stream>>>(esrc, edst, degout, degin, E);
    scan_kernel<<<1, 1024, 0, stream>>>(degin, rowstart, n);
    perm_kernel<<<(E + 255) / 256, 256, 0, stream>>>(edst, rowstart, cursor, perm, E);
    gather_src_kernel<<<(E + 255) / 256, 256, 0, stream>>>(esrc, perm, E);
    rs_kernel<<<(n + 255) / 256, 256, 0, stream>>>(degout, degin, rs_out, rs_in, n);
    const int* csrc = perm;

    auto gemm = [&](auto mf_tag, auto om_tag, const unsigned short* A, const float* Bm,
                    const float* bias, const float* rsc, void* Cp,
                    const float* fnum, const float* fden, int M, int Nb, int K, int ldc) {
        constexpr int MF = decltype(mf_tag)::value;
        constexpr int OM = decltype(om_tag)::value;
        dim3 grid((M + 64 * MF - 1) / (64 * MF), Nb / 64);
        gemm_v6<MF, OM><<<grid, 256, 0, stream>>>(A, Bm, bias, rsc, Cp, fnum, fden, M, Nb, K, ldc);
    };
    using I1 = std::integral_constant<int, 1>;
    using I2 = std::integral_constant<int, 2>;
    using O0 = std::integral_constant<int, 0>;
    using O1 = std::integral_constant<int, 1>;
    using O2 = std::integral_constant<int, 2>;

    // ---- modality encoders -> stackFT f32 + stackBF bf16
    {
        dim3 grid(n / 32, 1, 3);
        enc_mfma3<<<grid, 256, 0, stream>>>(text, audio, vision, W_text, W_audio, W_vision,
                                            b_text, b_audio, b_vision, stackFT, stackBF, n);
    }

    // ---- BiLSTM
    lstm_pre<<<(n * 32 + 255) / 256, 256, 0, stream>>>(stackFT, Wih_f, Wih_b,
                                                       bih_f, bhh_f, bih_b, bhh_b, xWf, xWb, n);
    lstm_seq2<<<(2 * B + 3) / 4, 64, 0, stream>>>(xWf, xWb, Whh_f, Whh_b, newF, B);

    // ---- GraphConv imputation + L1 norm -> hbufBF (bf16)
    gemm(I1{}, O0{}, stackBF, W_gc, nullptr, rs_out, big0, nullptr, nullptr, n, 192, 192, 192);
    gc_combine3<<<(n + 3) / 4, 256, 0, stream>>>(stackFT, big0, rowstart, csrc, rs_in, b_gc, hbufBF, n);

    // ---- gat2: packed src|dst|res GEMM -> big0 f32 [n,192], fused edge -> h3
    pack3_kernel<<<(192 * 192 + 255) / 256, 256, 0, stream>>>(Wsrc2, Wdst2, Wres2, bsrc2, bdst2, pw, pb, 192, 64);
    gemm(I1{}, O0{}, hbufBF, pw, pb, nullptr, big0, nullptr, nullptr, n, 192, 192, 192);
    gat_edge4<<<(n + 15) / 16, 256, 0, stream>>>(big0, 192, attn2, rowstart, csrc, h3, n);

    // ---- gat0: packed src|dst GEMM -> big0 bf16 [n,1024]; edge -> big2/den;
    //            res GEMM with fused finalize -> big1 bf16 [n,512]
    pack2_kernel<<<(192 * 1024 + 255) / 256, 256, 0, stream>>>(Wsrc0, Wdst0, bsrc0, bdst0, pw, pb, 192, 512);
    gemm(I2{}, O1{}, hbufBF, pw, pb, nullptr, big0, nullptr, nullptr, n, 1024, 192, 1024);
    gat_edge32<<<(n + 1) / 2, 256, 0, stream>>>((const unsigned short*)big0, attn0, rowstart, csrc, big2, den, n);
    gemm(I1{}, O2{}, hbufBF, Wres0, nullptr, nullptr, big1, big2, den, n, 512, 192, 512);

    // ---- gat1: packed src|dst|res GEMM (A = big1 bf16 [n,512]) -> big0 f32 [n,192], fused edge -> h1s
    pack3_kernel<<<(512 * 192 + 255) / 256, 256, 0, stream>>>(Wsrc1, Wdst1, Wres1, bsrc1, bdst1, pw, pb, 512, 64);
    gemm(I1{}, O0{}, (const unsigned short*)big1, pw, pb, nullptr, big0, nullptr, nullptr, n, 192, 512, 192);
    gat_edge4<<<(n + 15) / 16, 256, 0, stream>>>(big0, 192, attn1, rowstart, csrc, h1s, n);

    // ---- final classifier
    final_lin<<<(n * 6 + 255) / 256, 256, 0, stream>>>(h1s, newF, h3, W_lin, b_lin, out, n);
}

// Round 7
// 387.288 us; speedup vs baseline: 1.5042x; 1.0262x over previous
//
#include <hip/hip_runtime.h>

typedef __attribute__((ext_vector_type(8))) short short8;
typedef __attribute__((ext_vector_type(4))) float f32x4;
typedef _Float16 half8v __attribute__((ext_vector_type(8)));
typedef _Float16 half4v __attribute__((ext_vector_type(4)));

__device__ __forceinline__ unsigned short f2bf(float f) {
    unsigned u = __float_as_uint(f);
    u += 0x7FFFu + ((u >> 16) & 1u);
    return (unsigned short)(u >> 16);
}
__device__ __forceinline__ float bf2f(unsigned short h) {
    return __uint_as_float((unsigned)h << 16);
}

// =====================================================================
// gemm_v7: C[M,Nb] = A[M,K](bf16) @ B[K,Nb](bf16, pre-packed) (+bias)(*rowscale)
// A staged coalesced to LDS [BM][32] (bank-floor); B column-per-lane; reg prefetch.
// OUTMODE: 0 = f32 out, 1 = bf16 out, 2 = bf16 out + fused GAT finalize
template<int MF, int OUTMODE>
__global__ __launch_bounds__(256)
void gemm_v7(const unsigned short* __restrict__ A, const unsigned short* __restrict__ B,
             const float* __restrict__ bias, const float* __restrict__ rowscale,
             void* __restrict__ Cv, const float* __restrict__ fin_num,
             const float* __restrict__ fin_den,
             int M, int Nb, int K, int ldc)
{
    __shared__ alignas(16) unsigned short As[MF * 64 * 32];
    __shared__ alignas(16) unsigned short Bs[4 * 64 * 8];
    const int t = threadIdx.x;
    const int w = t >> 6, l = t & 63;
    const int r16 = l & 15, kg = l >> 4;
    const int row0 = blockIdx.x * (64 * MF);
    const int col0 = blockIdx.y * 64;
    const int bcol = t & 63, bkg = t >> 6;

    f32x4 acc[MF][4] = {};
    const short8 z8 = {0, 0, 0, 0, 0, 0, 0, 0};

    // per-thread staging coords
    int srow[MF], sch[MF];
    bool va[MF];
    const unsigned short* aptr[MF];
#pragma unroll
    for (int it = 0; it < MF; ++it) {
        int idx = it * 256 + t;
        srow[it] = idx >> 2; sch[it] = idx & 3;
        int gm = row0 + srow[it];
        va[it] = gm < M;
        aptr[it] = A + (size_t)gm * K + sch[it] * 8;
    }
    const unsigned short* bptr = B + (size_t)(bkg * 8) * Nb + col0 + bcol;

    short8 pa[MF];
    unsigned short pbv[8];
#pragma unroll
    for (int it = 0; it < MF; ++it)
        pa[it] = va[it] ? *reinterpret_cast<const short8*>(aptr[it]) : z8;
#pragma unroll
    for (int j = 0; j < 8; ++j) pbv[j] = bptr[(size_t)j * Nb];

    for (int k0 = 0; k0 < K; k0 += 32) {
#pragma unroll
        for (int it = 0; it < MF; ++it)
            *reinterpret_cast<short8*>(&As[srow[it] * 32 + sch[it] * 8]) = pa[it];
        {
            short8 hv;
#pragma unroll
            for (int j = 0; j < 8; ++j) hv[j] = (short)pbv[j];
            *reinterpret_cast<short8*>(&Bs[bkg * 512 + bcol * 8]) = hv;
        }
        __syncthreads();
        if (k0 + 32 < K) {
#pragma unroll
            for (int it = 0; it < MF; ++it)
                pa[it] = va[it] ? *reinterpret_cast<const short8*>(aptr[it] + k0 + 32) : z8;
#pragma unroll
            for (int j = 0; j < 8; ++j) pbv[j] = bptr[(size_t)(k0 + 32 + j) * Nb];
        }
        short8 af[MF];
#pragma unroll
        for (int mi = 0; mi < MF; ++mi)
            af[mi] = *reinterpret_cast<const short8*>(&As[((w * MF + mi) * 16 + r16) * 32 + kg * 8]);
#pragma unroll
        for (int ni = 0; ni < 4; ++ni) {
            short8 bf = *reinterpret_cast<const short8*>(&Bs[kg * 512 + (ni * 16 + r16) * 8]);
#pragma unroll
            for (int mi = 0; mi < MF; ++mi)
                acc[mi][ni] = __builtin_amdgcn_mfma_f32_16x16x32_bf16(af[mi], bf, acc[mi][ni], 0, 0, 0);
        }
        __syncthreads();
    }
#pragma unroll
    for (int mi = 0; mi < MF; ++mi)
#pragma unroll
        for (int ni = 0; ni < 4; ++ni) {
            int col = col0 + ni * 16 + r16;
            float bv = bias ? bias[col] : 0.f;
#pragma unroll
            for (int r = 0; r < 4; ++r) {
                int gm = row0 + (w * MF + mi) * 16 + kg * 4 + r;
                if (gm < M) {
                    float val = acc[mi][ni][r] + bv;
                    if (rowscale) val *= rowscale[gm];
                    size_t idx = (size_t)gm * ldc + col;
                    if (OUTMODE == 0) {
                        ((float*)Cv)[idx] = val;
                    } else if (OUTMODE == 1) {
                        ((unsigned short*)Cv)[idx] = f2bf(val);
                    } else {
                        float d = fin_den[(size_t)gm * 16 + (col >> 5)];
                        float inv = (d > 0.f) ? __fdividef(1.f, d) : 0.f;
                        float o = fmaxf(fin_num[idx] * inv + val, 0.f);
                        ((unsigned short*)Cv)[idx] = f2bf(o);
                    }
                }
            }
        }
}

// =====================================================================
// encoder: single-pass f16 MFMA, weights pre-converted to f16, reg prefetch.
// BM=32; wave w -> m-frag (w&1), col half (w>>1). grid (M/32, 1, 3)
__global__ __launch_bounds__(256)
void enc_f16(const float* __restrict__ text, const float* __restrict__ audio, const float* __restrict__ vision,
             const _Float16* __restrict__ Wf16,
             const float* __restrict__ bt, const float* __restrict__ ba, const float* __restrict__ bv,
             float* __restrict__ Cf, unsigned short* __restrict__ Cb, int M)
{
    __shared__ alignas(16) _Float16 Af[32 * 32];
    __shared__ alignas(16) _Float16 Bf[4 * 64 * 8];
    const int z = blockIdx.z;
    const float* A  = (z == 0) ? text : (z == 1) ? audio : vision;
    const _Float16* W = Wf16 + ((z == 0) ? 0 : (z == 1) ? 65536 : 98304);
    const float* bb = (z == 0) ? bt : (z == 1) ? ba : bv;
    const int K = (z == 1) ? 512 : 1024;

    const int t = threadIdx.x;
    const int w = t >> 6, l = t & 63;
    const int r16 = l & 15, kg = l >> 4;
    const int row0 = blockIdx.x * 32;
    const int mi = w & 1;
    const int ncol0 = (w >> 1) * 32;
    const int arow = t >> 3, ac8 = t & 7;
    const int bcol = t & 63, bkg = t >> 6;

    const float* ap = A + (size_t)(row0 + arow) * K + ac8 * 4;
    const _Float16* wp = W + (size_t)(bkg * 8) * 64 + bcol;

    float4 pa = *reinterpret_cast<const float4*>(ap);
    _Float16 pb[8];
#pragma unroll
    for (int j = 0; j < 8; ++j) pb[j] = wp[(size_t)j * 64];

    f32x4 acc[2] = {};
    for (int k0 = 0; k0 < K; k0 += 32) {
        {
            half4v av;
            av[0] = (_Float16)pa.x; av[1] = (_Float16)pa.y;
            av[2] = (_Float16)pa.z; av[3] = (_Float16)pa.w;
            *reinterpret_cast<half4v*>(&Af[arow * 32 + ac8 * 4]) = av;
            half8v bv8;
#pragma unroll
            for (int j = 0; j < 8; ++j) bv8[j] = pb[j];
            *reinterpret_cast<half8v*>(&Bf[bkg * 512 + bcol * 8]) = bv8;
        }
        __syncthreads();
        if (k0 + 32 < K) {
            pa = *reinterpret_cast<const float4*>(ap + k0 + 32);
#pragma unroll
            for (int j = 0; j < 8; ++j) pb[j] = wp[(size_t)(k0 + 32 + j) * 64];
        }
        half8v af = *reinterpret_cast<const half8v*>(&Af[(mi * 16 + r16) * 32 + kg * 8]);
#pragma unroll
        for (int ni = 0; ni < 2; ++ni) {
            half8v bf = *reinterpret_cast<const half8v*>(&Bf[kg * 512 + (ncol0 + ni * 16 + r16) * 8]);
            acc[ni] = __builtin_amdgcn_mfma_f32_16x16x32_f16(af, bf, acc[ni], 0, 0, 0);
        }
        __syncthreads();
    }
#pragma unroll
    for (int ni = 0; ni < 2; ++ni) {
        int col = ncol0 + ni * 16 + r16;
        float bvv = bb[col];
#pragma unroll
        for (int r = 0; r < 4; ++r) {
            int gr = row0 + mi * 16 + kg * 4 + r;
            if (gr < M) {
                float val = acc[ni][r] + bvv;
                size_t idx = (size_t)gr * 192 + z * 64 + col;
                Cf[idx] = val;
                Cb[idx] = f2bf(val);
            }
        }
    }
}

// ---------------- weight packing (all emit bf16 weights / f32 bias)
__global__ void pack3b(const float* __restrict__ W0, const float* __restrict__ W1, const float* __restrict__ W2,
                       const float* __restrict__ b0, const float* __restrict__ b1,
                       unsigned short* __restrict__ Wp, float* __restrict__ bp, int K, int O)
{
    int gid = blockIdx.x * blockDim.x + threadIdx.x;
    int O3 = 3 * O;
    if (gid < O3) bp[gid] = (gid < O) ? b0[gid] : (gid < 2 * O) ? b1[gid - O] : 0.f;
    if (gid >= K * O3) return;
    int k = gid / O3, c = gid - k * O3;
    float v = (c < O) ? W0[k * O + c] : (c < 2 * O) ? W1[k * O + c - O] : W2[k * O + c - 2 * O];
    Wp[gid] = f2bf(v);
}

__global__ void pack2b(const float* __restrict__ W0, const float* __restrict__ W1,
                       const float* __restrict__ b0, const float* __restrict__ b1,
                       unsigned short* __restrict__ Wp, float* __restrict__ bp, int K, int O)
{
    int gid = blockIdx.x * blockDim.x + threadIdx.x;
    int O2 = 2 * O;
    if (gid < O2) bp[gid] = (gid < O) ? b0[gid] : b1[gid - O];
    if (gid >= K * O2) return;
    int k = gid / O2, c = gid - k * O2;
    Wp[gid] = f2bf((c < O) ? W0[k * O + c] : W1[k * O + c - O]);
}

__global__ void pack1b(const float* __restrict__ W, unsigned short* __restrict__ Wp, int cnt)
{
    int gid = blockIdx.x * blockDim.x + threadIdx.x;
    if (gid < cnt) Wp[gid] = f2bf(W[gid]);
}

__global__ void pack_encw(const float* __restrict__ Wt, const float* __restrict__ Wa, const float* __restrict__ Wv,
                          _Float16* __restrict__ out)
{
    int gid = blockIdx.x * blockDim.x + threadIdx.x;
    if (gid >= 163840) return;
    float v;
    if (gid < 65536) v = Wt[gid];
    else if (gid < 98304) v = Wa[gid - 65536];
    else v = Wv[gid - 98304];
    out[gid] = (_Float16)v;
}

// ---------------- graph preprocessing
__global__ void deg_kernel(const int* __restrict__ src, const int* __restrict__ dst,
                           int* degout, int* degin, int E)
{
    int e = blockIdx.x * blockDim.x + threadIdx.x;
    if (e < E) {
        atomicAdd(&degout[src[e]], 1);
        atomicAdd(&degin[dst[e]], 1);
    }
}

__global__ __launch_bounds__(1024)
void scan_kernel(const int* __restrict__ degin, int* __restrict__ rowstart, int n)
{
    __shared__ int part[1024];
    int t = threadIdx.x;
    int chunk = (n + 1023) / 1024;
    int s = 0;
    for (int i = 0; i < chunk; ++i) {
        int idx = t * chunk + i;
        if (idx < n) s += degin[idx];
    }
    part[t] = s;
    __syncthreads();
    for (int o = 1; o < 1024; o <<= 1) {
        int v = (t >= o) ? part[t - o] : 0;
        __syncthreads();
        part[t] += v;
        __syncthreads();
    }
    int run = (t > 0) ? part[t - 1] : 0;
    for (int i = 0; i < chunk; ++i) {
        int idx = t * chunk + i;
        if (idx < n) { rowstart[idx] = run; run += degin[idx]; }
    }
    if (t == 1023) rowstart[n] = part[1023];
}

__global__ void perm_kernel(const int* __restrict__ dst, const int* __restrict__ rowstart,
                            int* cursor, int* __restrict__ perm, int E)
{
    int e = blockIdx.x * blockDim.x + threadIdx.x;
    if (e < E) {
        int v = dst[e];
        int p = atomicAdd(&cursor[v], 1);
        perm[rowstart[v] + p] = e;
    }
}

__global__ void gather_src_kernel(const int* __restrict__ esrc, int* perm, int E)
{
    int i = blockIdx.x * blockDim.x + threadIdx.x;
    if (i < E) perm[i] = esrc[perm[i]];
}

__global__ void rs_kernel(const int* degout, const int* degin, float* rso, float* rsi, int n)
{
    int i = blockIdx.x * blockDim.x + threadIdx.x;
    if (i < n) {
        rso[i] = rsqrtf((float)max(degout[i], 1));
        rsi[i] = rsqrtf((float)max(degin[i], 1));
    }
}

// ---------------- LSTM
__global__ void lstm_pre(const float* __restrict__ x, const float* __restrict__ Wf,
                         const float* __restrict__ Wb,
                         const float* bf1, const float* bf2, const float* bb1, const float* bb2,
                         float* __restrict__ xWf, float* __restrict__ xWb, int n)
{
    int gid = blockIdx.x * blockDim.x + threadIdx.x;
    if (gid >= n * 32) return;
    int nn = gid >> 5, r = gid & 31, d = r >> 4, j = r & 15;
    const float* W = (d ? Wb : Wf) + j * 192;
    const float* xr = x + (size_t)nn * 192;
    float s = 0.f;
#pragma unroll 4
    for (int k = 0; k < 192; k += 4) {
        float4 xv = *reinterpret_cast<const float4*>(xr + k);
        float4 wv = *reinterpret_cast<const float4*>(W + k);
        s += xv.x * wv.x + xv.y * wv.y + xv.z * wv.z + xv.w * wv.w;
    }
    s += d ? (bb1[j] + bb2[j]) : (bf1[j] + bf2[j]);
    int b = nn / 120, tt = nn - b * 120;
    (d ? xWb : xWf)[((size_t)b * 16 + j) * 120 + tt] = s;
}

__device__ __forceinline__ float fsigm(float x) { return __fdividef(1.f, 1.f + __expf(-x)); }
__device__ __forceinline__ float ftanh(float x) { return 1.f - __fdividef(2.f, __expf(2.f * x) + 1.f); }

template<int DIR>
__device__ void lstm_chain(const float* __restrict__ xw, const float* __restrict__ whh,
                           float* __restrict__ newF, int b)
{
    int j = threadIdx.x & 15;
    int k = j & 3;
    float4 w = *reinterpret_cast<const float4*>(whh + j * 4);
    const float* xp = xw + ((size_t)b * 16 + j) * 120;
    float h0 = 0.f, h1 = 0.f, h2 = 0.f, h3 = 0.f, cst = 0.f;
    int tb0 = DIR ? 108 : 0;
    float4 a0 = *reinterpret_cast<const float4*>(xp + tb0);
    float4 a1 = *reinterpret_cast<const float4*>(xp + tb0 + 4);
    float4 a2 = *reinterpret_cast<const float4*>(xp + tb0 + 8);
    for (int ch = 0; ch < 10; ++ch) {
        float4 b0 = a0, b1 = a1, b2 = a2;
        if (ch < 9) {
            int nt = DIR ? (96 - ch * 12) : (12 + ch * 12);
            b0 = *reinterpret_cast<const float4*>(xp + nt);
            b1 = *reinterpret_cast<const float4*>(xp + nt + 4);
            b2 = *reinterpret_cast<const float4*>(xp + nt + 8);
        }
        float zz[12] = {a0.x, a0.y, a0.z, a0.w, a1.x, a1.y, a1.z, a1.w, a2.x, a2.y, a2.z, a2.w};
        int tbase = DIR ? (108 - ch * 12) : (ch * 12);
#pragma unroll
        for (int ii = 0; ii < 12; ++ii) {
            int idx = DIR ? (11 - ii) : ii;
            float z = zz[idx] + ((w.x * h0 + w.y * h1) + (w.z * h2 + w.w * h3));
            float zi = __shfl(z, k, 16);
            float zf = __shfl(z, k + 4, 16);
            float zg = __shfl(z, k + 8, 16);
            float zo = __shfl(z, k + 12, 16);
            float ig = fsigm(zi), fg = fsigm(zf), gg = ftanh(zg), og = fsigm(zo);
            cst = fg * cst + ig * gg;
            float hn = og * ftanh(cst);
            h0 = __shfl(hn, 0, 16); h1 = __shfl(hn, 1, 16);
            h2 = __shfl(hn, 2, 16); h3 = __shfl(hn, 3, 16);
            if (j < 4) newF[((size_t)b * 120 + tbase + idx) * 8 + DIR * 4 + j] = hn;
        }
        a0 = b0; a1 = b1; a2 = b2;
    }
}

__global__ __launch_bounds__(64)
void lstm_seq2(const float* __restrict__ xWf, const float* __restrict__ xWb,
               const float* __restrict__ Whhf, const float* __restrict__ Whhb,
               float* __restrict__ newF, int B)
{
    int sub = threadIdx.x >> 4;
    int chain = blockIdx.x * 4 + sub;
    if (chain >= 2 * B) return;
    int d = chain / B;
    int b = chain - d * B;
    if (d == 0) lstm_chain<0>(xWf, Whhf, newF, b);
    else        lstm_chain<1>(xWb, Whhb, newF, b);
}

// ---------------- GraphConv combine + L1 norm: bf16 hw gather, bf16 h out
__global__ __launch_bounds__(256)
void gc_combine4(const float* __restrict__ stackFT, const unsigned short* __restrict__ hw,
                 const int* __restrict__ rowstart, const int* __restrict__ csrc,
                 const float* __restrict__ rs_in,
                 const float* __restrict__ b_gc, unsigned short* __restrict__ hB, int n)
{
    int v = blockIdx.x * 4 + (threadIdx.x >> 6);
    int l = threadIdx.x & 63;
    if (v >= n) return;
    int s0 = rowstart[v], s1 = rowstart[v + 1];
    float sum0 = 0.f, sum1 = 0.f, sum2 = 0.f;
    int u = (s0 < s1) ? csrc[s0] : 0;
    for (int i = s0; i < s1; ++i) {
        int un = (i + 1 < s1) ? csrc[i + 1] : 0;
        const unsigned short* hr = hw + (size_t)u * 192 + l;
        sum0 += bf2f(hr[0]); sum1 += bf2f(hr[64]); sum2 += bf2f(hr[128]);
        u = un;
    }
    float ri = rs_in[v];
    const float* sf = stackFT + (size_t)v * 192 + l;
    float v0 = 0.5f * (sf[0]   + sum0 * ri + b_gc[l]);
    float v1 = 0.5f * (sf[64]  + sum1 * ri + b_gc[l + 64]);
    float v2 = 0.5f * (sf[128] + sum2 * ri + b_gc[l + 128]);
    float r = fabsf(v0) + fabsf(v1) + fabsf(v2);
#pragma unroll
    for (int o = 32; o; o >>= 1) r += __shfl_xor(r, o);
    float inv = __fdividef(1.f, fmaxf(r, 1e-12f));
    unsigned short* hp = hB + (size_t)v * 192 + l;
    hp[0]   = f2bf(v0 * inv);
    hp[64]  = f2bf(v1 * inv);
    hp[128] = f2bf(v2 * inv);
}

// ---------------- GATv2 F=4 (HF=64): bf16 base, 16 lanes/node, fused epilogue
__global__ __launch_bounds__(256)
void gat_edge4b(const unsigned short* __restrict__ base, // [n,192] bf16 fs|fd|res
                const float* __restrict__ attn,
                const int* __restrict__ rowstart, const int* __restrict__ csrc,
                float* __restrict__ outp, int n)
{
    int v = blockIdx.x * 16 + (threadIdx.x >> 4);
    int l = threadIdx.x & 15;
    if (v >= n) return;
    float4 at = *reinterpret_cast<const float4*>(attn + l * 4);
    ushort4 fdu = *reinterpret_cast<const ushort4*>(base + (size_t)v * 192 + 64 + l * 4);
    float4 fdv = make_float4(bf2f(fdu.x), bf2f(fdu.y), bf2f(fdu.z), bf2f(fdu.w));
    float4 acc = make_float4(0.f, 0.f, 0.f, 0.f);
    float dn = 0.f;
    int s0 = rowstart[v], s1 = rowstart[v + 1];
    int u = (s0 < s1) ? csrc[s0] : 0;
    ushort4 su = (s0 < s1) ? *reinterpret_cast<const ushort4*>(base + (size_t)u * 192 + l * 4)
                           : make_ushort4(0, 0, 0, 0);
    for (int i = s0; i < s1; ++i) {
        int un = (i + 1 < s1) ? csrc[i + 1] : 0;
        ushort4 sun = (i + 1 < s1) ? *reinterpret_cast<const ushort4*>(base + (size_t)un * 192 + l * 4)
                                   : make_ushort4(0, 0, 0, 0);
        float4 sv = make_float4(bf2f(su.x), bf2f(su.y), bf2f(su.z), bf2f(su.w));
        float ex_, ey, ez, ew;
        ex_ = sv.x + fdv.x; ex_ = (ex_ > 0.f) ? ex_ : 0.2f * ex_;
        ey  = sv.y + fdv.y; ey  = (ey  > 0.f) ? ey  : 0.2f * ey;
        ez  = sv.z + fdv.z; ez  = (ez  > 0.f) ? ez  : 0.2f * ez;
        ew  = sv.w + fdv.w; ew  = (ew  > 0.f) ? ew  : 0.2f * ew;
        float p = ex_ * at.x + ey * at.y + ez * at.z + ew * at.w;
        float ex = __expf(p);
        acc.x += ex * sv.x; acc.y += ex * sv.y; acc.z += ex * sv.z; acc.w += ex * sv.w;
        dn += ex;
        su = sun; u = un;
    }
    ushort4 ru = *reinterpret_cast<const ushort4*>(base + (size_t)v * 192 + 128 + l * 4);
    float inv = (dn > 0.f) ? __fdividef(1.f, dn) : 0.f;
    float4 o;
    o.x = fmaxf(acc.x * inv + bf2f(ru.x), 0.f);
    o.y = fmaxf(acc.y * inv + bf2f(ru.y), 0.f);
    o.z = fmaxf(acc.z * inv + bf2f(ru.z), 0.f);
    o.w = fmaxf(acc.w * inv + bf2f(ru.w), 0.f);
    *reinterpret_cast<float4*>(outp + (size_t)v * 64 + l * 4) = o;
}

// ---------------- GATv2 F=32 (HF=512): bf16 fs|fd, 128 lanes/node, 8-lane head reduce
__global__ __launch_bounds__(256)
void gat_edge32(const unsigned short* __restrict__ base,   // [n,1024] bf16 fs|fd
                const float* __restrict__ attn,
                const int* __restrict__ rowstart, const int* __restrict__ csrc,
                float* __restrict__ num, float* __restrict__ den, int n)
{
    int v = blockIdx.x * 2 + (threadIdx.x >> 7);
    int l = threadIdx.x & 127;
    if (v >= n) return;
    int head = l >> 3;
    float4 at = *reinterpret_cast<const float4*>(attn + head * 32 + (l & 7) * 4);
    ushort4 fdu = *reinterpret_cast<const ushort4*>(base + (size_t)v * 1024 + 512 + l * 4);
    float4 fdv = make_float4(bf2f(fdu.x), bf2f(fdu.y), bf2f(fdu.z), bf2f(fdu.w));
    float4 acc = make_float4(0.f, 0.f, 0.f, 0.f);
    float dn = 0.f;
    int s0 = rowstart[v], s1 = rowstart[v + 1];
    int u = (s0 < s1) ? csrc[s0] : 0;
    ushort4 su = (s0 < s1) ? *reinterpret_cast<const ushort4*>(base + (size_t)u * 1024 + l * 4)
                           : make_ushort4(0, 0, 0, 0);
    for (int i = s0; i < s1; ++i) {
        int un = (i + 1 < s1) ? csrc[i + 1] : 0;
        ushort4 sun = (i + 1 < s1) ? *reinterpret_cast<const ushort4*>(base + (size_t)un * 1024 + l * 4)
                                   : make_ushort4(0, 0, 0, 0);
        float4 sv = make_float4(bf2f(su.x), bf2f(su.y), bf2f(su.z), bf2f(su.w));
        float ex_, ey, ez, ew;
        ex_ = sv.x + fdv.x; ex_ = (ex_ > 0.f) ? ex_ : 0.2f * ex_;
        ey  = sv.y + fdv.y; ey  = (ey  > 0.f) ? ey  : 0.2f * ey;
        ez  = sv.z + fdv.z; ez  = (ez  > 0.f) ? ez  : 0.2f * ez;
        ew  = sv.w + fdv.w; ew  = (ew  > 0.f) ? ew  : 0.2f * ew;
        float p = ex_ * at.x + ey * at.y + ez * at.z + ew * at.w;
        p += __shfl_xor(p, 1, 8);
        p += __shfl_xor(p, 2, 8);
        p += __shfl_xor(p, 4, 8);
        float ex = __expf(p);
        acc.x += ex * sv.x; acc.y += ex * sv.y; acc.z += ex * sv.z; acc.w += ex * sv.w;
        dn += ex;
        su = sun; u = un;
    }
    *reinterpret_cast<float4*>(num + (size_t)v * 512 + l * 4) = acc;
    if ((l & 7) == 0) den[(size_t)v * 16 + head] = dn;
}

// ---------------- final classifier
__global__ void final_lin(const float* __restrict__ h1, const float* __restrict__ newF,
                          const float* __restrict__ h3, const float* __restrict__ W,
                          const float* __restrict__ bias, float* __restrict__ out, int n)
{
    int gid = blockIdx.x * blockDim.x + threadIdx.x;
    if (gid >= n * 6) return;
    int v = gid / 6, o = gid - v * 6;
    float s = bias[o];
    const float* a = h1 + (size_t)v * 64;
#pragma unroll 8
    for (int r = 0; r < 64; ++r) s += a[r] * W[r * 6 + o];
    const float* b = newF + (size_t)v * 8;
#pragma unroll
    for (int r = 0; r < 8; ++r) s += b[r] * W[(64 + r) * 6 + o];
    const float* c = h3 + (size_t)v * 64;
#pragma unroll 8
    for (int r = 0; r < 64; ++r) s += c[r] * W[(72 + r) * 6 + o];
    out[gid] = s;
}

// ----------------------------------------------------------------------------
extern "C" void kernel_launch(void* const* d_in, const int* in_sizes, int n_in,
                              void* d_out, int out_size, void* d_ws, size_t ws_size,
                              hipStream_t stream)
{
    const float* text   = (const float*)d_in[0];
    const float* audio  = (const float*)d_in[1];
    const float* vision = (const float*)d_in[2];
    const int*   esrc   = (const int*)d_in[3];
    const int*   edst   = (const int*)d_in[4];
    const float* W_audio = (const float*)d_in[5];  const float* b_audio = (const float*)d_in[6];
    const float* W_vision= (const float*)d_in[7];  const float* b_vision= (const float*)d_in[8];
    const float* W_text  = (const float*)d_in[9];  const float* b_text  = (const float*)d_in[10];
    const float* Wih_f = (const float*)d_in[11]; const float* Whh_f = (const float*)d_in[12];
    const float* bih_f = (const float*)d_in[13]; const float* bhh_f = (const float*)d_in[14];
    const float* Wih_b = (const float*)d_in[15]; const float* Whh_b = (const float*)d_in[16];
    const float* bih_b = (const float*)d_in[17]; const float* bhh_b = (const float*)d_in[18];
    const float* W_gc  = (const float*)d_in[19]; const float* b_gc  = (const float*)d_in[20];
    const float* Wsrc2 = (const float*)d_in[21]; const float* bsrc2 = (const float*)d_in[22];
    const float* Wdst2 = (const float*)d_in[23]; const float* bdst2 = (const float*)d_in[24];
    const float* attn2 = (const float*)d_in[25]; const float* Wres2 = (const float*)d_in[26];
    const float* Wsrc0 = (const float*)d_in[27]; const float* bsrc0 = (const float*)d_in[28];
    const float* Wdst0 = (const float*)d_in[29]; const float* bdst0 = (const float*)d_in[30];
    const float* attn0 = (const float*)d_in[31]; const float* Wres0 = (const float*)d_in[32];
    const float* Wsrc1 = (const float*)d_in[33]; const float* bsrc1 = (const float*)d_in[34];
    const float* Wdst1 = (const float*)d_in[35]; const float* bdst1 = (const float*)d_in[36];
    const float* attn1 = (const float*)d_in[37]; const float* Wres1 = (const float*)d_in[38];
    const float* W_lin = (const float*)d_in[39]; const float* b_lin = (const float*)d_in[40];
    float* out = (float*)d_out;

    const int n = in_sizes[0] / 1024;   // 12000
    const int E = in_sizes[3];          // 192000
    const int B = n / 120;              // 100

    // ---- workspace carve (256B aligned)
    char* p = (char*)d_ws;
    auto alloc_f = [&](size_t cnt) { float* r = (float*)p; p += ((cnt * 4 + 255) / 256) * 256; return r; };
    auto alloc_h = [&](size_t cnt) { unsigned short* r = (unsigned short*)p; p += ((cnt * 2 + 255) / 256) * 256; return r; };
    auto alloc_i = [&](size_t cnt) { int* r = (int*)p; p += ((cnt * 4 + 255) / 256) * 256; return r; };
    float*          stackFT = alloc_f((size_t)n * 192);
    unsigned short* stackBF = alloc_h((size_t)n * 192);
    unsigned short* hbufBF  = alloc_h((size_t)n * 192);
    unsigned short* encW    = alloc_h(163840);           // f16 enc weights
    float* xWf     = alloc_f((size_t)n * 16);
    float* xWb     = alloc_f((size_t)n * 16);
    float* newF    = alloc_f((size_t)n * 8);
    float* big0    = alloc_f((size_t)n * 512);  // bf16 multi-use: gc hw[n,192] -> gat2 out -> gat0 out[n,1024] -> gat1 out
    float* big1    = alloc_f((size_t)n * 512);  // res0-fused bf16 out [n,512]
    float* big2    = alloc_f((size_t)n * 512);  // gat0 num f32 [n,512]
    float* den     = alloc_f((size_t)n * 16);
    float* h3      = alloc_f((size_t)n * 64);
    float* h1s     = alloc_f((size_t)n * 64);   // packed-weight scratch until gat1 edge
    float* rs_out  = alloc_f(n);
    float* rs_in   = alloc_f(n);
    int* zero_base = alloc_i((size_t)3 * n);
    int* degout = zero_base;
    int* degin  = zero_base + n;
    int* cursor = zero_base + 2 * n;
    int* rowstart = alloc_i((size_t)n + 1);
    int* perm     = alloc_i((size_t)E);
    if ((size_t)(p - (char*)d_ws) > ws_size) return;

    unsigned short* pw = (unsigned short*)h1s;   // ≤ 196608 ushorts
    float* pb = h1s + 120000;                    // ≤ 1536 floats

    // ---- graph preprocessing
    hipMemsetAsync(zero_base, 0, (size_t)3 * n * 4, stream);
    deg_kernel<<<(E + 255) / 256, 256, 0, stream>>>(esrc, edst, degout, degin, E);
    scan_kernel<<<1, 1024, 0, stream>>>(degin, rowstart, n);
    perm_kernel<<<(E + 255) / 256, 256, 0, stream>>>(edst, rowstart, cursor, perm, E);
    gather_src_kernel<<<(E + 255) / 256, 256, 0, stream>>>(esrc, perm, E);
    rs_kernel<<<(n + 255) / 256, 256, 0, stream>>>(degout, degin, rs_out, rs_in, n);
    const int* csrc = perm;

    auto gemm = [&](auto mf_tag, auto om_tag, const unsigned short* A, const unsigned short* Bm,
                    const float* bias, const float* rsc, void* Cp,
                    const float* fnum, const float* fden, int M, int Nb, int K, int ldc) {
        constexpr int MF = decltype(mf_tag)::value;
        constexpr int OM = decltype(om_tag)::value;
        dim3 grid((M + 64 * MF - 1) / (64 * MF), Nb / 64);
        gemm_v7<MF, OM><<<grid, 256, 0, stream>>>(A, Bm, bias, rsc, Cp, fnum, fden, M, Nb, K, ldc);
    };
    using I1 = std::integral_constant<int, 1>;
    using I2 = std::integral_constant<int, 2>;
    using O1 = std::integral_constant<int, 1>;
    using O2 = std::integral_constant<int, 2>;

    // ---- modality encoders (f16 MFMA) -> stackFT f32 + stackBF bf16
    pack_encw<<<(163840 + 255) / 256, 256, 0, stream>>>(W_text, W_audio, W_vision, (_Float16*)encW);
    {
        dim3 grid(n / 32, 1, 3);
        enc_f16<<<grid, 256, 0, stream>>>(text, audio, vision, (const _Float16*)encW,
                                          b_text, b_audio, b_vision, stackFT, stackBF, n);
    }

    // ---- BiLSTM
    lstm_pre<<<(n * 32 + 255) / 256, 256, 0, stream>>>(stackFT, Wih_f, Wih_b,
                                                       bih_f, bhh_f, bih_b, bhh_b, xWf, xWb, n);
    lstm_seq2<<<(2 * B + 3) / 4, 64, 0, stream>>>(xWf, xWb, Whh_f, Whh_b, newF, B);

    // ---- GraphConv imputation + L1 norm -> hbufBF (bf16)
    pack1b<<<(192 * 192 + 255) / 256, 256, 0, stream>>>(W_gc, pw, 192 * 192);
    gemm(I1{}, O1{}, stackBF, pw, nullptr, rs_out, big0, nullptr, nullptr, n, 192, 192, 192);
    gc_combine4<<<(n + 3) / 4, 256, 0, stream>>>(stackFT, (const unsigned short*)big0,
                                                 rowstart, csrc, rs_in, b_gc, hbufBF, n);

    // ---- gat2: packed src|dst|res GEMM -> big0 bf16 [n,192], fused edge -> h3
    pack3b<<<(192 * 192 + 255) / 256, 256, 0, stream>>>(Wsrc2, Wdst2, Wres2, bsrc2, bdst2, pw, pb, 192, 64);
    gemm(I1{}, O1{}, hbufBF, pw, pb, nullptr, big0, nullptr, nullptr, n, 192, 192, 192);
    gat_edge4b<<<(n + 15) / 16, 256, 0, stream>>>((const unsigned short*)big0, attn2, rowstart, csrc, h3, n);

    // ---- gat0: packed src|dst GEMM -> big0 bf16 [n,1024]; edge -> big2/den;
    //            res GEMM with fused finalize -> big1 bf16 [n,512]
    pack2b<<<(192 * 1024 + 255) / 256, 256, 0, stream>>>(Wsrc0, Wdst0, bsrc0, bdst0, pw, pb, 192, 512);
    gemm(I2{}, O1{}, hbufBF, pw, pb, nullptr, big0, nullptr, nullptr, n, 1024, 192, 1024);
    gat_edge32<<<(n + 1) / 2, 256, 0, stream>>>((const unsigned short*)big0, attn0, rowstart, csrc, big2, den, n);
    pack1b<<<(192 * 512 + 255) / 256, 256, 0, stream>>>(Wres0, pw, 192 * 512);
    gemm(I1{}, O2{}, hbufBF, pw, nullptr, nullptr, big1, big2, den, n, 512, 192, 512);

    // ---- gat1: packed src|dst|res GEMM (A = big1 bf16 [n,512]) -> big0 bf16 [n,192], fused edge -> h1s
    pack3b<<<(512 * 192 + 255) / 256, 256, 0, stream>>>(Wsrc1, Wdst1, Wres1, bsrc1, bdst1, pw, pb, 512, 64);
    gemm(I1{}, O1{}, (const unsigned short*)big1, pw, pb, nullptr, big0, nullptr, nullptr, n, 192, 512, 192);
    gat_edge4b<<<(n + 15) / 16, 256, 0, stream>>>((const unsigned short*)big0, attn1, rowstart, csrc, h1s, n);

    // ---- final classifier
    final_lin<<<(n * 6 + 255) / 256, 256, 0, stream>>>(h1s, newF, h3, W_lin, b_lin, out, n);
}

// Round 8
// 350.267 us; speedup vs baseline: 1.6632x; 1.1057x over previous
//
#include <hip/hip_runtime.h>

typedef __attribute__((ext_vector_type(8))) short short8;
typedef __attribute__((ext_vector_type(4))) float f32x4;
typedef _Float16 half8v __attribute__((ext_vector_type(8)));
typedef _Float16 half4v __attribute__((ext_vector_type(4)));

__device__ __forceinline__ unsigned short f2bf(float f) {
    unsigned u = __float_as_uint(f);
    u += 0x7FFFu + ((u >> 16) & 1u);
    return (unsigned short)(u >> 16);
}
__device__ __forceinline__ float bf2f(unsigned short h) {
    return __uint_as_float((unsigned)h << 16);
}

// =====================================================================
// gemm_v7: C[M,Nb] = A[M,K](bf16) @ B[K,Nb](bf16, pre-packed) (+bias)(*rowscale)
template<int MF, int OUTMODE>
__global__ __launch_bounds__(256)
void gemm_v7(const unsigned short* __restrict__ A, const unsigned short* __restrict__ B,
             const float* __restrict__ bias, const float* __restrict__ rowscale,
             void* __restrict__ Cv, const float* __restrict__ fin_num,
             const float* __restrict__ fin_den,
             int M, int Nb, int K, int ldc)
{
    __shared__ alignas(16) unsigned short As[MF * 64 * 32];
    __shared__ alignas(16) unsigned short Bs[4 * 64 * 8];
    const int t = threadIdx.x;
    const int w = t >> 6, l = t & 63;
    const int r16 = l & 15, kg = l >> 4;
    const int row0 = blockIdx.x * (64 * MF);
    const int col0 = blockIdx.y * 64;
    const int bcol = t & 63, bkg = t >> 6;

    f32x4 acc[MF][4] = {};
    const short8 z8 = {0, 0, 0, 0, 0, 0, 0, 0};

    int srow[MF], sch[MF];
    bool va[MF];
    const unsigned short* aptr[MF];
#pragma unroll
    for (int it = 0; it < MF; ++it) {
        int idx = it * 256 + t;
        srow[it] = idx >> 2; sch[it] = idx & 3;
        int gm = row0 + srow[it];
        va[it] = gm < M;
        aptr[it] = A + (size_t)gm * K + sch[it] * 8;
    }
    const unsigned short* bptr = B + (size_t)(bkg * 8) * Nb + col0 + bcol;

    short8 pa[MF];
    unsigned short pbv[8];
#pragma unroll
    for (int it = 0; it < MF; ++it)
        pa[it] = va[it] ? *reinterpret_cast<const short8*>(aptr[it]) : z8;
#pragma unroll
    for (int j = 0; j < 8; ++j) pbv[j] = bptr[(size_t)j * Nb];

    for (int k0 = 0; k0 < K; k0 += 32) {
#pragma unroll
        for (int it = 0; it < MF; ++it)
            *reinterpret_cast<short8*>(&As[srow[it] * 32 + sch[it] * 8]) = pa[it];
        {
            short8 hv;
#pragma unroll
            for (int j = 0; j < 8; ++j) hv[j] = (short)pbv[j];
            *reinterpret_cast<short8*>(&Bs[bkg * 512 + bcol * 8]) = hv;
        }
        __syncthreads();
        if (k0 + 32 < K) {
#pragma unroll
            for (int it = 0; it < MF; ++it)
                pa[it] = va[it] ? *reinterpret_cast<const short8*>(aptr[it] + k0 + 32) : z8;
#pragma unroll
            for (int j = 0; j < 8; ++j) pbv[j] = bptr[(size_t)(k0 + 32 + j) * Nb];
        }
        short8 af[MF];
#pragma unroll
        for (int mi = 0; mi < MF; ++mi)
            af[mi] = *reinterpret_cast<const short8*>(&As[((w * MF + mi) * 16 + r16) * 32 + kg * 8]);
#pragma unroll
        for (int ni = 0; ni < 4; ++ni) {
            short8 bf = *reinterpret_cast<const short8*>(&Bs[kg * 512 + (ni * 16 + r16) * 8]);
#pragma unroll
            for (int mi = 0; mi < MF; ++mi)
                acc[mi][ni] = __builtin_amdgcn_mfma_f32_16x16x32_bf16(af[mi], bf, acc[mi][ni], 0, 0, 0);
        }
        __syncthreads();
    }
#pragma unroll
    for (int mi = 0; mi < MF; ++mi)
#pragma unroll
        for (int ni = 0; ni < 4; ++ni) {
            int col = col0 + ni * 16 + r16;
            float bv = bias ? bias[col] : 0.f;
#pragma unroll
            for (int r = 0; r < 4; ++r) {
                int gm = row0 + (w * MF + mi) * 16 + kg * 4 + r;
                if (gm < M) {
                    float val = acc[mi][ni][r] + bv;
                    if (rowscale) val *= rowscale[gm];
                    size_t idx = (size_t)gm * ldc + col;
                    if (OUTMODE == 0) {
                        ((float*)Cv)[idx] = val;
                    } else if (OUTMODE == 1) {
                        ((unsigned short*)Cv)[idx] = f2bf(val);
                    } else {
                        float d = fin_den[(size_t)gm * 16 + (col >> 5)];
                        float inv = (d > 0.f) ? __fdividef(1.f, d) : 0.f;
                        float o = fmaxf(fin_num[idx] * inv + val, 0.f);
                        ((unsigned short*)Cv)[idx] = f2bf(o);
                    }
                }
            }
        }
}

// =====================================================================
// encoder: single-pass f16 MFMA, weights pre-converted to f16, reg prefetch.
__global__ __launch_bounds__(256)
void enc_f16(const float* __restrict__ text, const float* __restrict__ audio, const float* __restrict__ vision,
             const _Float16* __restrict__ Wf16,
             const float* __restrict__ bt, const float* __restrict__ ba, const float* __restrict__ bv,
             float* __restrict__ Cf, unsigned short* __restrict__ Cb, int M)
{
    __shared__ alignas(16) _Float16 Af[32 * 32];
    __shared__ alignas(16) _Float16 Bf[4 * 64 * 8];
    const int z = blockIdx.z;
    const float* A  = (z == 0) ? text : (z == 1) ? audio : vision;
    const _Float16* W = Wf16 + ((z == 0) ? 0 : (z == 1) ? 65536 : 98304);
    const float* bb = (z == 0) ? bt : (z == 1) ? ba : bv;
    const int K = (z == 1) ? 512 : 1024;

    const int t = threadIdx.x;
    const int w = t >> 6, l = t & 63;
    const int r16 = l & 15, kg = l >> 4;
    const int row0 = blockIdx.x * 32;
    const int mi = w & 1;
    const int ncol0 = (w >> 1) * 32;
    const int arow = t >> 3, ac8 = t & 7;
    const int bcol = t & 63, bkg = t >> 6;

    const float* ap = A + (size_t)(row0 + arow) * K + ac8 * 4;
    const _Float16* wp = W + (size_t)(bkg * 8) * 64 + bcol;

    float4 pa = *reinterpret_cast<const float4*>(ap);
    _Float16 pb[8];
#pragma unroll
    for (int j = 0; j < 8; ++j) pb[j] = wp[(size_t)j * 64];

    f32x4 acc[2] = {};
    for (int k0 = 0; k0 < K; k0 += 32) {
        {
            half4v av;
            av[0] = (_Float16)pa.x; av[1] = (_Float16)pa.y;
            av[2] = (_Float16)pa.z; av[3] = (_Float16)pa.w;
            *reinterpret_cast<half4v*>(&Af[arow * 32 + ac8 * 4]) = av;
            half8v bv8;
#pragma unroll
            for (int j = 0; j < 8; ++j) bv8[j] = pb[j];
            *reinterpret_cast<half8v*>(&Bf[bkg * 512 + bcol * 8]) = bv8;
        }
        __syncthreads();
        if (k0 + 32 < K) {
            pa = *reinterpret_cast<const float4*>(ap + k0 + 32);
#pragma unroll
            for (int j = 0; j < 8; ++j) pb[j] = wp[(size_t)(k0 + 32 + j) * 64];
        }
        half8v af = *reinterpret_cast<const half8v*>(&Af[(mi * 16 + r16) * 32 + kg * 8]);
#pragma unroll
        for (int ni = 0; ni < 2; ++ni) {
            half8v bf = *reinterpret_cast<const half8v*>(&Bf[kg * 512 + (ncol0 + ni * 16 + r16) * 8]);
            acc[ni] = __builtin_amdgcn_mfma_f32_16x16x32_f16(af, bf, acc[ni], 0, 0, 0);
        }
        __syncthreads();
    }
#pragma unroll
    for (int ni = 0; ni < 2; ++ni) {
        int col = ncol0 + ni * 16 + r16;
        float bvv = bb[col];
#pragma unroll
        for (int r = 0; r < 4; ++r) {
            int gr = row0 + mi * 16 + kg * 4 + r;
            if (gr < M) {
                float val = acc[ni][r] + bvv;
                size_t idx = (size_t)gr * 192 + z * 64 + col;
                Cf[idx] = val;
                Cb[idx] = f2bf(val);
            }
        }
    }
}

// ---------------- weight packing
__global__ void pack3b(const float* __restrict__ W0, const float* __restrict__ W1, const float* __restrict__ W2,
                       const float* __restrict__ b0, const float* __restrict__ b1,
                       unsigned short* __restrict__ Wp, float* __restrict__ bp, int K, int O)
{
    int gid = blockIdx.x * blockDim.x + threadIdx.x;
    int O3 = 3 * O;
    if (gid < O3) bp[gid] = (gid < O) ? b0[gid] : (gid < 2 * O) ? b1[gid - O] : 0.f;
    if (gid >= K * O3) return;
    int k = gid / O3, c = gid - k * O3;
    float v = (c < O) ? W0[k * O + c] : (c < 2 * O) ? W1[k * O + c - O] : W2[k * O + c - 2 * O];
    Wp[gid] = f2bf(v);
}

__global__ void pack2b(const float* __restrict__ W0, const float* __restrict__ W1,
                       const float* __restrict__ b0, const float* __restrict__ b1,
                       unsigned short* __restrict__ Wp, float* __restrict__ bp, int K, int O)
{
    int gid = blockIdx.x * blockDim.x + threadIdx.x;
    int O2 = 2 * O;
    if (gid < O2) bp[gid] = (gid < O) ? b0[gid] : b1[gid - O];
    if (gid >= K * O2) return;
    int k = gid / O2, c = gid - k * O2;
    Wp[gid] = f2bf((c < O) ? W0[k * O + c] : W1[k * O + c - O]);
}

__global__ void pack1b(const float* __restrict__ W, unsigned short* __restrict__ Wp, int cnt)
{
    int gid = blockIdx.x * blockDim.x + threadIdx.x;
    if (gid < cnt) Wp[gid] = f2bf(W[gid]);
}

__global__ void pack_encw(const float* __restrict__ Wt, const float* __restrict__ Wa, const float* __restrict__ Wv,
                          _Float16* __restrict__ out)
{
    int gid = blockIdx.x * blockDim.x + threadIdx.x;
    if (gid >= 163840) return;
    float v;
    if (gid < 65536) v = Wt[gid];
    else if (gid < 98304) v = Wa[gid - 65536];
    else v = Wv[gid - 98304];
    out[gid] = (_Float16)v;
}

// ---------------- graph preprocessing
__global__ void deg_kernel(const int* __restrict__ src, const int* __restrict__ dst,
                           int* degout, int* degin, int E)
{
    int e = blockIdx.x * blockDim.x + threadIdx.x;
    if (e < E) {
        atomicAdd(&degout[src[e]], 1);
        atomicAdd(&degin[dst[e]], 1);
    }
}

__global__ __launch_bounds__(1024)
void scan_kernel(const int* __restrict__ degin, int* __restrict__ rowstart, int n)
{
    __shared__ int part[1024];
    int t = threadIdx.x;
    int chunk = (n + 1023) / 1024;
    int s = 0;
    for (int i = 0; i < chunk; ++i) {
        int idx = t * chunk + i;
        if (idx < n) s += degin[idx];
    }
    part[t] = s;
    __syncthreads();
    for (int o = 1; o < 1024; o <<= 1) {
        int v = (t >= o) ? part[t - o] : 0;
        __syncthreads();
        part[t] += v;
        __syncthreads();
    }
    int run = (t > 0) ? part[t - 1] : 0;
    for (int i = 0; i < chunk; ++i) {
        int idx = t * chunk + i;
        if (idx < n) { rowstart[idx] = run; run += degin[idx]; }
    }
    if (t == 1023) rowstart[n] = part[1023];
}

__global__ void perm_kernel(const int* __restrict__ dst, const int* __restrict__ rowstart,
                            int* cursor, int* __restrict__ perm, int E)
{
    int e = blockIdx.x * blockDim.x + threadIdx.x;
    if (e < E) {
        int v = dst[e];
        int p = atomicAdd(&cursor[v], 1);
        perm[rowstart[v] + p] = e;
    }
}

__global__ void gather_src_kernel(const int* __restrict__ esrc, int* perm, int E)
{
    int i = blockIdx.x * blockDim.x + threadIdx.x;
    if (i < E) perm[i] = esrc[perm[i]];
}

__global__ void rs_kernel(const int* degout, const int* degin, float* rso, float* rsi, int n)
{
    int i = blockIdx.x * blockDim.x + threadIdx.x;
    if (i < n) {
        rso[i] = rsqrtf((float)max(degout[i], 1));
        rsi[i] = rsqrtf((float)max(degin[i], 1));
    }
}

// ---------------- LSTM
__global__ void lstm_pre(const float* __restrict__ x, const float* __restrict__ Wf,
                         const float* __restrict__ Wb,
                         const float* bf1, const float* bf2, const float* bb1, const float* bb2,
                         float* __restrict__ xWf, float* __restrict__ xWb, int n)
{
    int gid = blockIdx.x * blockDim.x + threadIdx.x;
    if (gid >= n * 32) return;
    int nn = gid >> 5, r = gid & 31, d = r >> 4, j = r & 15;
    const float* W = (d ? Wb : Wf) + j * 192;
    const float* xr = x + (size_t)nn * 192;
    float s = 0.f;
#pragma unroll 4
    for (int k = 0; k < 192; k += 4) {
        float4 xv = *reinterpret_cast<const float4*>(xr + k);
        float4 wv = *reinterpret_cast<const float4*>(W + k);
        s += xv.x * wv.x + xv.y * wv.y + xv.z * wv.z + xv.w * wv.w;
    }
    s += d ? (bb1[j] + bb2[j]) : (bf1[j] + bf2[j]);
    int b = nn / 120, tt = nn - b * 120;
    (d ? xWb : xWf)[((size_t)b * 16 + j) * 120 + tt] = s;
}

__device__ __forceinline__ float fsigm(float x) { return __fdividef(1.f, 1.f + __expf(-x)); }
__device__ __forceinline__ float ftanh(float x) { return 1.f - __fdividef(2.f, __expf(2.f * x) + 1.f); }

template<int DIR>
__device__ void lstm_chain(const float* __restrict__ xw, const float* __restrict__ whh,
                           float* __restrict__ newF, int b)
{
    int j = threadIdx.x & 15;
    int k = j & 3;
    float4 w = *reinterpret_cast<const float4*>(whh + j * 4);
    const float* xp = xw + ((size_t)b * 16 + j) * 120;
    float h0 = 0.f, h1 = 0.f, h2 = 0.f, h3 = 0.f, cst = 0.f;
    int tb0 = DIR ? 108 : 0;
    float4 a0 = *reinterpret_cast<const float4*>(xp + tb0);
    float4 a1 = *reinterpret_cast<const float4*>(xp + tb0 + 4);
    float4 a2 = *reinterpret_cast<const float4*>(xp + tb0 + 8);
    for (int ch = 0; ch < 10; ++ch) {
        float4 b0 = a0, b1 = a1, b2 = a2;
        if (ch < 9) {
            int nt = DIR ? (96 - ch * 12) : (12 + ch * 12);
            b0 = *reinterpret_cast<const float4*>(xp + nt);
            b1 = *reinterpret_cast<const float4*>(xp + nt + 4);
            b2 = *reinterpret_cast<const float4*>(xp + nt + 8);
        }
        float zz[12] = {a0.x, a0.y, a0.z, a0.w, a1.x, a1.y, a1.z, a1.w, a2.x, a2.y, a2.z, a2.w};
        int tbase = DIR ? (108 - ch * 12) : (ch * 12);
#pragma unroll
        for (int ii = 0; ii < 12; ++ii) {
            int idx = DIR ? (11 - ii) : ii;
            float z = zz[idx] + ((w.x * h0 + w.y * h1) + (w.z * h2 + w.w * h3));
            float zi = __shfl(z, k, 16);
            float zf = __shfl(z, k + 4, 16);
            float zg = __shfl(z, k + 8, 16);
            float zo = __shfl(z, k + 12, 16);
            float ig = fsigm(zi), fg = fsigm(zf), gg = ftanh(zg), og = fsigm(zo);
            cst = fg * cst + ig * gg;
            float hn = og * ftanh(cst);
            h0 = __shfl(hn, 0, 16); h1 = __shfl(hn, 1, 16);
            h2 = __shfl(hn, 2, 16); h3 = __shfl(hn, 3, 16);
            if (j < 4) newF[((size_t)b * 120 + tbase + idx) * 8 + DIR * 4 + j] = hn;
        }
        a0 = b0; a1 = b1; a2 = b2;
    }
}

__global__ __launch_bounds__(64)
void lstm_seq2(const float* __restrict__ xWf, const float* __restrict__ xWb,
               const float* __restrict__ Whhf, const float* __restrict__ Whhb,
               float* __restrict__ newF, int B)
{
    int sub = threadIdx.x >> 4;
    int chain = blockIdx.x * 4 + sub;
    if (chain >= 2 * B) return;
    int d = chain / B;
    int b = chain - d * B;
    if (d == 0) lstm_chain<0>(xWf, Whhf, newF, b);
    else        lstm_chain<1>(xWb, Whhb, newF, b);
}

// ---------------- GraphConv combine + L1 norm: 2-edge software pipeline
__global__ __launch_bounds__(256)
void gc_combine5(const float* __restrict__ stackFT, const unsigned short* __restrict__ hw,
                 const int* __restrict__ rowstart, const int* __restrict__ csrc,
                 const float* __restrict__ rs_in,
                 const float* __restrict__ b_gc, unsigned short* __restrict__ hB, int n)
{
    int v = blockIdx.x * 4 + (threadIdx.x >> 6);
    int l = threadIdx.x & 63;
    if (v >= n) return;
    int s0 = rowstart[v], s1 = rowstart[v + 1];
    float sum0 = 0.f, sum1 = 0.f, sum2 = 0.f;

    unsigned short a0 = 0, a1 = 0, a2 = 0, b0 = 0, b1 = 0, b2 = 0;
    auto LD = [&](int i, unsigned short& x0, unsigned short& x1, unsigned short& x2) {
        const unsigned short* hr = hw + (size_t)csrc[i] * 192 + l;
        x0 = hr[0]; x1 = hr[64]; x2 = hr[128];
    };
    int i = s0;
    if (i < s1) LD(i, a0, a1, a2);
    if (i + 1 < s1) LD(i + 1, b0, b1, b2);
    for (; i + 2 < s1; i += 2) {
        unsigned short n0, n1, n2, m0 = 0, m1 = 0, m2 = 0;
        LD(i + 2, n0, n1, n2);
        if (i + 3 < s1) LD(i + 3, m0, m1, m2);
        sum0 += bf2f(a0) + bf2f(b0);
        sum1 += bf2f(a1) + bf2f(b1);
        sum2 += bf2f(a2) + bf2f(b2);
        a0 = n0; a1 = n1; a2 = n2; b0 = m0; b1 = m1; b2 = m2;
    }
    if (i < s1) { sum0 += bf2f(a0); sum1 += bf2f(a1); sum2 += bf2f(a2); }
    if (i + 1 < s1) { sum0 += bf2f(b0); sum1 += bf2f(b1); sum2 += bf2f(b2); }

    float ri = rs_in[v];
    const float* sf = stackFT + (size_t)v * 192 + l;
    float v0 = 0.5f * (sf[0]   + sum0 * ri + b_gc[l]);
    float v1 = 0.5f * (sf[64]  + sum1 * ri + b_gc[l + 64]);
    float v2 = 0.5f * (sf[128] + sum2 * ri + b_gc[l + 128]);
    float r = fabsf(v0) + fabsf(v1) + fabsf(v2);
#pragma unroll
    for (int o = 32; o; o >>= 1) r += __shfl_xor(r, o);
    float inv = __fdividef(1.f, fmaxf(r, 1e-12f));
    unsigned short* hp = hB + (size_t)v * 192 + l;
    hp[0]   = f2bf(v0 * inv);
    hp[64]  = f2bf(v1 * inv);
    hp[128] = f2bf(v2 * inv);
}

// ---------------- GATv2 F=4 (HF=64): 16 lanes/node, 2-edge pipeline, fused epilogue
__global__ __launch_bounds__(256)
void gat_edge4c(const unsigned short* __restrict__ base, // [n,192] bf16 fs|fd|res
                const float* __restrict__ attn,
                const int* __restrict__ rowstart, const int* __restrict__ csrc,
                float* __restrict__ outp, int n)
{
    int v = blockIdx.x * 16 + (threadIdx.x >> 4);
    int l = threadIdx.x & 15;
    if (v >= n) return;
    float4 at = *reinterpret_cast<const float4*>(attn + l * 4);
    ushort4 fdu = *reinterpret_cast<const ushort4*>(base + (size_t)v * 192 + 64 + l * 4);
    float fd0 = bf2f(fdu.x), fd1 = bf2f(fdu.y), fd2 = bf2f(fdu.z), fd3 = bf2f(fdu.w);
    float ac0 = 0.f, ac1 = 0.f, ac2 = 0.f, ac3 = 0.f, dn = 0.f;
    int s0 = rowstart[v], s1 = rowstart[v + 1];

    auto LD = [&](int i) -> ushort4 {
        return *reinterpret_cast<const ushort4*>(base + (size_t)csrc[i] * 192 + l * 4);
    };
    auto ACC = [&](ushort4 su) {
        float s0f = bf2f(su.x), s1f = bf2f(su.y), s2f = bf2f(su.z), s3f = bf2f(su.w);
        float e0 = s0f + fd0; e0 = fmaxf(e0, 0.2f * e0);
        float e1 = s1f + fd1; e1 = fmaxf(e1, 0.2f * e1);
        float e2 = s2f + fd2; e2 = fmaxf(e2, 0.2f * e2);
        float e3 = s3f + fd3; e3 = fmaxf(e3, 0.2f * e3);
        float p = e0 * at.x + e1 * at.y + e2 * at.z + e3 * at.w;
        float ex = __expf(p);
        ac0 += ex * s0f; ac1 += ex * s1f; ac2 += ex * s2f; ac3 += ex * s3f;
        dn += ex;
    };
    const ushort4 zu = make_ushort4(0, 0, 0, 0);
    ushort4 c0 = zu, c1 = zu;
    int i = s0;
    if (i < s1) c0 = LD(i);
    if (i + 1 < s1) c1 = LD(i + 1);
    for (; i + 2 < s1; i += 2) {
        ushort4 n0 = LD(i + 2);
        ushort4 n1 = (i + 3 < s1) ? LD(i + 3) : zu;
        ACC(c0); ACC(c1);
        c0 = n0; c1 = n1;
    }
    if (i < s1) ACC(c0);
    if (i + 1 < s1) ACC(c1);

    ushort4 ru = *reinterpret_cast<const ushort4*>(base + (size_t)v * 192 + 128 + l * 4);
    float inv = (dn > 0.f) ? __fdividef(1.f, dn) : 0.f;
    float4 o;
    o.x = fmaxf(ac0 * inv + bf2f(ru.x), 0.f);
    o.y = fmaxf(ac1 * inv + bf2f(ru.y), 0.f);
    o.z = fmaxf(ac2 * inv + bf2f(ru.z), 0.f);
    o.w = fmaxf(ac3 * inv + bf2f(ru.w), 0.f);
    *reinterpret_cast<float4*>(outp + (size_t)v * 64 + l * 4) = o;
}

// ---------------- GATv2 F=32 (HF=512): one wave per node, 8 elems/lane, 2-edge pipeline
__global__ __launch_bounds__(256)
void gat_edge32b(const unsigned short* __restrict__ base,   // [n,1024] bf16 fs|fd
                 const float* __restrict__ attn,
                 const int* __restrict__ rowstart, const int* __restrict__ csrc,
                 float* __restrict__ num, float* __restrict__ den, int n)
{
    int v = blockIdx.x * 4 + (threadIdx.x >> 6);
    int l = threadIdx.x & 63;        // lane: elems [l*8, l*8+8), head = l>>2
    if (v >= n) return;
    float at[8];
    {
        float4 aA = *reinterpret_cast<const float4*>(attn + l * 8);
        float4 aB = *reinterpret_cast<const float4*>(attn + l * 8 + 4);
        at[0] = aA.x; at[1] = aA.y; at[2] = aA.z; at[3] = aA.w;
        at[4] = aB.x; at[5] = aB.y; at[6] = aB.z; at[7] = aB.w;
    }
    float fd[8];
    {
        short8 fdu = *reinterpret_cast<const short8*>(base + (size_t)v * 1024 + 512 + l * 8);
#pragma unroll
        for (int j = 0; j < 8; ++j) fd[j] = bf2f((unsigned short)fdu[j]);
    }
    float acc[8] = {};
    float dn = 0.f;
    int s0 = rowstart[v], s1 = rowstart[v + 1];

    auto LD = [&](int i) -> short8 {
        return *reinterpret_cast<const short8*>(base + (size_t)csrc[i] * 1024 + l * 8);
    };
    auto ACC = [&](short8 su) {
        float sf[8];
        float p = 0.f;
#pragma unroll
        for (int j = 0; j < 8; ++j) {
            sf[j] = bf2f((unsigned short)su[j]);
            float e = sf[j] + fd[j];
            e = fmaxf(e, 0.2f * e);
            p += e * at[j];
        }
        p += __shfl_xor(p, 1, 4);
        p += __shfl_xor(p, 2, 4);
        float ex = __expf(p);
#pragma unroll
        for (int j = 0; j < 8; ++j) acc[j] += ex * sf[j];
        dn += ex;
    };
    const short8 z8 = {0, 0, 0, 0, 0, 0, 0, 0};
    short8 c0 = z8, c1 = z8;
    int i = s0;
    if (i < s1) c0 = LD(i);
    if (i + 1 < s1) c1 = LD(i + 1);
    for (; i + 2 < s1; i += 2) {          // all guards wave-uniform (one node per wave)
        short8 n0 = LD(i + 2);
        short8 n1 = (i + 3 < s1) ? LD(i + 3) : z8;
        ACC(c0); ACC(c1);
        c0 = n0; c1 = n1;
    }
    if (i < s1) ACC(c0);
    if (i + 1 < s1) ACC(c1);

    float* np = num + (size_t)v * 512 + l * 8;
    *reinterpret_cast<float4*>(np)     = make_float4(acc[0], acc[1], acc[2], acc[3]);
    *reinterpret_cast<float4*>(np + 4) = make_float4(acc[4], acc[5], acc[6], acc[7]);
    if ((l & 3) == 0) den[(size_t)v * 16 + (l >> 2)] = dn;
}

// ---------------- final classifier
__global__ void final_lin(const float* __restrict__ h1, const float* __restrict__ newF,
                          const float* __restrict__ h3, const float* __restrict__ W,
                          const float* __restrict__ bias, float* __restrict__ out, int n)
{
    int gid = blockIdx.x * blockDim.x + threadIdx.x;
    if (gid >= n * 6) return;
    int v = gid / 6, o = gid - v * 6;
    float s = bias[o];
    const float* a = h1 + (size_t)v * 64;
#pragma unroll 8
    for (int r = 0; r < 64; ++r) s += a[r] * W[r * 6 + o];
    const float* b = newF + (size_t)v * 8;
#pragma unroll
    for (int r = 0; r < 8; ++r) s += b[r] * W[(64 + r) * 6 + o];
    const float* c = h3 + (size_t)v * 64;
#pragma unroll 8
    for (int r = 0; r < 64; ++r) s += c[r] * W[(72 + r) * 6 + o];
    out[gid] = s;
}

// ----------------------------------------------------------------------------
extern "C" void kernel_launch(void* const* d_in, const int* in_sizes, int n_in,
                              void* d_out, int out_size, void* d_ws, size_t ws_size,
                              hipStream_t stream)
{
    const float* text   = (const float*)d_in[0];
    const float* audio  = (const float*)d_in[1];
    const float* vision = (const float*)d_in[2];
    const int*   esrc   = (const int*)d_in[3];
    const int*   edst   = (const int*)d_in[4];
    const float* W_audio = (const float*)d_in[5];  const float* b_audio = (const float*)d_in[6];
    const float* W_vision= (const float*)d_in[7];  const float* b_vision= (const float*)d_in[8];
    const float* W_text  = (const float*)d_in[9];  const float* b_text  = (const float*)d_in[10];
    const float* Wih_f = (const float*)d_in[11]; const float* Whh_f = (const float*)d_in[12];
    const float* bih_f = (const float*)d_in[13]; const float* bhh_f = (const float*)d_in[14];
    const float* Wih_b = (const float*)d_in[15]; const float* Whh_b = (const float*)d_in[16];
    const float* bih_b = (const float*)d_in[17]; const float* bhh_b = (const float*)d_in[18];
    const float* W_gc  = (const float*)d_in[19]; const float* b_gc  = (const float*)d_in[20];
    const float* Wsrc2 = (const float*)d_in[21]; const float* bsrc2 = (const float*)d_in[22];
    const float* Wdst2 = (const float*)d_in[23]; const float* bdst2 = (const float*)d_in[24];
    const float* attn2 = (const float*)d_in[25]; const float* Wres2 = (const float*)d_in[26];
    const float* Wsrc0 = (const float*)d_in[27]; const float* bsrc0 = (const float*)d_in[28];
    const float* Wdst0 = (const float*)d_in[29]; const float* bdst0 = (const float*)d_in[30];
    const float* attn0 = (const float*)d_in[31]; const float* Wres0 = (const float*)d_in[32];
    const float* Wsrc1 = (const float*)d_in[33]; const float* bsrc1 = (const float*)d_in[34];
    const float* Wdst1 = (const float*)d_in[35]; const float* bdst1 = (const float*)d_in[36];
    const float* attn1 = (const float*)d_in[37]; const float* Wres1 = (const float*)d_in[38];
    const float* W_lin = (const float*)d_in[39]; const float* b_lin = (const float*)d_in[40];
    float* out = (float*)d_out;

    const int n = in_sizes[0] / 1024;   // 12000
    const int E = in_sizes[3];          // 192000
    const int B = n / 120;              // 100

    // ---- workspace carve (256B aligned)
    char* p = (char*)d_ws;
    auto alloc_f = [&](size_t cnt) { float* r = (float*)p; p += ((cnt * 4 + 255) / 256) * 256; return r; };
    auto alloc_h = [&](size_t cnt) { unsigned short* r = (unsigned short*)p; p += ((cnt * 2 + 255) / 256) * 256; return r; };
    auto alloc_i = [&](size_t cnt) { int* r = (int*)p; p += ((cnt * 4 + 255) / 256) * 256; return r; };
    float*          stackFT = alloc_f((size_t)n * 192);
    unsigned short* stackBF = alloc_h((size_t)n * 192);
    unsigned short* hbufBF  = alloc_h((size_t)n * 192);
    unsigned short* encW    = alloc_h(163840);
    float* xWf     = alloc_f((size_t)n * 16);
    float* xWb     = alloc_f((size_t)n * 16);
    float* newF    = alloc_f((size_t)n * 8);
    float* big0    = alloc_f((size_t)n * 512);
    float* big1    = alloc_f((size_t)n * 512);
    float* big2    = alloc_f((size_t)n * 512);
    float* den     = alloc_f((size_t)n * 16);
    float* h3      = alloc_f((size_t)n * 64);
    float* h1s     = alloc_f((size_t)n * 64);
    float* rs_out  = alloc_f(n);
    float* rs_in   = alloc_f(n);
    int* zero_base = alloc_i((size_t)3 * n);
    int* degout = zero_base;
    int* degin  = zero_base + n;
    int* cursor = zero_base + 2 * n;
    int* rowstart = alloc_i((size_t)n + 1);
    int* perm     = alloc_i((size_t)E);
    if ((size_t)(p - (char*)d_ws) > ws_size) return;

    unsigned short* pw = (unsigned short*)h1s;
    float* pb = h1s + 120000;

    // ---- graph preprocessing
    hipMemsetAsync(zero_base, 0, (size_t)3 * n * 4, stream);
    deg_kernel<<<(E + 255) / 256, 256, 0, stream>>>(esrc, edst, degout, degin, E);
    scan_kernel<<<1, 1024, 0, stream>>>(degin, rowstart, n);
    perm_kernel<<<(E + 255) / 256, 256, 0, stream>>>(edst, rowstart, cursor, perm, E);
    gather_src_kernel<<<(E + 255) / 256, 256, 0, stream>>>(esrc, perm, E);
    rs_kernel<<<(n + 255) / 256, 256, 0, stream>>>(degout, degin, rs_out, rs_in, n);
    const int* csrc = perm;

    auto gemm = [&](auto mf_tag, auto om_tag, const unsigned short* A, const unsigned short* Bm,
                    const float* bias, const float* rsc, void* Cp,
                    const float* fnum, const float* fden, int M, int Nb, int K, int ldc) {
        constexpr int MF = decltype(mf_tag)::value;
        constexpr int OM = decltype(om_tag)::value;
        dim3 grid((M + 64 * MF - 1) / (64 * MF), Nb / 64);
        gemm_v7<MF, OM><<<grid, 256, 0, stream>>>(A, Bm, bias, rsc, Cp, fnum, fden, M, Nb, K, ldc);
    };
    using I1 = std::integral_constant<int, 1>;
    using I2 = std::integral_constant<int, 2>;
    using O1 = std::integral_constant<int, 1>;
    using O2 = std::integral_constant<int, 2>;

    // ---- modality encoders (f16 MFMA) -> stackFT f32 + stackBF bf16
    pack_encw<<<(163840 + 255) / 256, 256, 0, stream>>>(W_text, W_audio, W_vision, (_Float16*)encW);
    {
        dim3 grid(n / 32, 1, 3);
        enc_f16<<<grid, 256, 0, stream>>>(text, audio, vision, (const _Float16*)encW,
                                          b_text, b_audio, b_vision, stackFT, stackBF, n);
    }

    // ---- BiLSTM
    lstm_pre<<<(n * 32 + 255) / 256, 256, 0, stream>>>(stackFT, Wih_f, Wih_b,
                                                       bih_f, bhh_f, bih_b, bhh_b, xWf, xWb, n);
    lstm_seq2<<<(2 * B + 3) / 4, 64, 0, stream>>>(xWf, xWb, Whh_f, Whh_b, newF, B);

    // ---- GraphConv imputation + L1 norm -> hbufBF (bf16)
    pack1b<<<(192 * 192 + 255) / 256, 256, 0, stream>>>(W_gc, pw, 192 * 192);
    gemm(I1{}, O1{}, stackBF, pw, nullptr, rs_out, big0, nullptr, nullptr, n, 192, 192, 192);
    gc_combine5<<<(n + 3) / 4, 256, 0, stream>>>(stackFT, (const unsigned short*)big0,
                                                 rowstart, csrc, rs_in, b_gc, hbufBF, n);

    // ---- gat2: packed src|dst|res GEMM -> big0 bf16 [n,192], fused edge -> h3
    pack3b<<<(192 * 192 + 255) / 256, 256, 0, stream>>>(Wsrc2, Wdst2, Wres2, bsrc2, bdst2, pw, pb, 192, 64);
    gemm(I1{}, O1{}, hbufBF, pw, pb, nullptr, big0, nullptr, nullptr, n, 192, 192, 192);
    gat_edge4c<<<(n + 15) / 16, 256, 0, stream>>>((const unsigned short*)big0, attn2, rowstart, csrc, h3, n);

    // ---- gat0: packed src|dst GEMM -> big0 bf16 [n,1024]; edge -> big2/den;
    //            res GEMM with fused finalize -> big1 bf16 [n,512]
    pack2b<<<(192 * 1024 + 255) / 256, 256, 0, stream>>>(Wsrc0, Wdst0, bsrc0, bdst0, pw, pb, 192, 512);
    gemm(I2{}, O1{}, hbufBF, pw, pb, nullptr, big0, nullptr, nullptr, n, 1024, 192, 1024);
    gat_edge32b<<<(n + 3) / 4, 256, 0, stream>>>((const unsigned short*)big0, attn0, rowstart, csrc, big2, den, n);
    pack1b<<<(192 * 512 + 255) / 256, 256, 0, stream>>>(Wres0, pw, 192 * 512);
    gemm(I1{}, O2{}, hbufBF, pw, nullptr, nullptr, big1, big2, den, n, 512, 192, 512);

    // ---- gat1: packed src|dst|res GEMM (A = big1 bf16 [n,512]) -> big0 bf16 [n,192], fused edge -> h1s
    pack3b<<<(512 * 192 + 255) / 256, 256, 0, stream>>>(Wsrc1, Wdst1, Wres1, bsrc1, bdst1, pw, pb, 512, 64);
    gemm(I1{}, O1{}, (const unsigned short*)big1, pw, pb, nullptr, big0, nullptr, nullptr, n, 192, 512, 192);
    gat_edge4c<<<(n + 15) / 16, 256, 0, stream>>>((const unsigned short*)big0, attn1, rowstart, csrc, h1s, n);

    // ---- final classifier
    final_lin<<<(n * 6 + 255) / 256, 256, 0, stream>>>(h1s, newF, h3, W_lin, b_lin, out, n);
}

// Round 9
// 344.175 us; speedup vs baseline: 1.6926x; 1.0177x over previous
//
#include <hip/hip_runtime.h>

typedef __attribute__((ext_vector_type(8))) short short8;
typedef __attribute__((ext_vector_type(4))) float f32x4;
typedef _Float16 half8v __attribute__((ext_vector_type(8)));

__device__ __forceinline__ unsigned short f2bf(float f) {
    unsigned u = __float_as_uint(f);
    u += 0x7FFFu + ((u >> 16) & 1u);
    return (unsigned short)(u >> 16);
}
__device__ __forceinline__ float bf2f(unsigned short h) {
    return __uint_as_float((unsigned)h << 16);
}

// =====================================================================
// gemm_v7: C[M,Nb] = A[M,K](bf16) @ B[K,Nb](bf16, pre-packed) (+bias)(*rowscale)
template<int MF, int OUTMODE>
__global__ __launch_bounds__(256)
void gemm_v7(const unsigned short* __restrict__ A, const unsigned short* __restrict__ B,
             const float* __restrict__ bias, const float* __restrict__ rowscale,
             void* __restrict__ Cv, const float* __restrict__ fin_num,
             const float* __restrict__ fin_den,
             int M, int Nb, int K, int ldc)
{
    __shared__ alignas(16) unsigned short As[MF * 64 * 32];
    __shared__ alignas(16) unsigned short Bs[4 * 64 * 8];
    const int t = threadIdx.x;
    const int w = t >> 6, l = t & 63;
    const int r16 = l & 15, kg = l >> 4;
    const int row0 = blockIdx.x * (64 * MF);
    const int col0 = blockIdx.y * 64;
    const int bcol = t & 63, bkg = t >> 6;

    f32x4 acc[MF][4] = {};
    const short8 z8 = {0, 0, 0, 0, 0, 0, 0, 0};

    int srow[MF], sch[MF];
    bool va[MF];
    const unsigned short* aptr[MF];
#pragma unroll
    for (int it = 0; it < MF; ++it) {
        int idx = it * 256 + t;
        srow[it] = idx >> 2; sch[it] = idx & 3;
        int gm = row0 + srow[it];
        va[it] = gm < M;
        aptr[it] = A + (size_t)gm * K + sch[it] * 8;
    }
    const unsigned short* bptr = B + (size_t)(bkg * 8) * Nb + col0 + bcol;

    short8 pa[MF];
    unsigned short pbv[8];
#pragma unroll
    for (int it = 0; it < MF; ++it)
        pa[it] = va[it] ? *reinterpret_cast<const short8*>(aptr[it]) : z8;
#pragma unroll
    for (int j = 0; j < 8; ++j) pbv[j] = bptr[(size_t)j * Nb];

    for (int k0 = 0; k0 < K; k0 += 32) {
#pragma unroll
        for (int it = 0; it < MF; ++it)
            *reinterpret_cast<short8*>(&As[srow[it] * 32 + sch[it] * 8]) = pa[it];
        {
            short8 hv;
#pragma unroll
            for (int j = 0; j < 8; ++j) hv[j] = (short)pbv[j];
            *reinterpret_cast<short8*>(&Bs[bkg * 512 + bcol * 8]) = hv;
        }
        __syncthreads();
        if (k0 + 32 < K) {
#pragma unroll
            for (int it = 0; it < MF; ++it)
                pa[it] = va[it] ? *reinterpret_cast<const short8*>(aptr[it] + k0 + 32) : z8;
#pragma unroll
            for (int j = 0; j < 8; ++j) pbv[j] = bptr[(size_t)(k0 + 32 + j) * Nb];
        }
        short8 af[MF];
#pragma unroll
        for (int mi = 0; mi < MF; ++mi)
            af[mi] = *reinterpret_cast<const short8*>(&As[((w * MF + mi) * 16 + r16) * 32 + kg * 8]);
#pragma unroll
        for (int ni = 0; ni < 4; ++ni) {
            short8 bf = *reinterpret_cast<const short8*>(&Bs[kg * 512 + (ni * 16 + r16) * 8]);
#pragma unroll
            for (int mi = 0; mi < MF; ++mi)
                acc[mi][ni] = __builtin_amdgcn_mfma_f32_16x16x32_bf16(af[mi], bf, acc[mi][ni], 0, 0, 0);
        }
        __syncthreads();
    }
#pragma unroll
    for (int mi = 0; mi < MF; ++mi)
#pragma unroll
        for (int ni = 0; ni < 4; ++ni) {
            int col = col0 + ni * 16 + r16;
            float bv = bias ? bias[col] : 0.f;
#pragma unroll
            for (int r = 0; r < 4; ++r) {
                int gm = row0 + (w * MF + mi) * 16 + kg * 4 + r;
                if (gm < M) {
                    float val = acc[mi][ni][r] + bv;
                    if (rowscale) val *= rowscale[gm];
                    size_t idx = (size_t)gm * ldc + col;
                    if (OUTMODE == 0) {
                        ((float*)Cv)[idx] = val;
                    } else if (OUTMODE == 1) {
                        ((unsigned short*)Cv)[idx] = f2bf(val);
                    } else {
                        float d = fin_den[(size_t)gm * 16 + (col >> 5)];
                        float inv = (d > 0.f) ? __fdividef(1.f, d) : 0.f;
                        float o = fmaxf(fin_num[idx] * inv + val, 0.f);
                        ((unsigned short*)Cv)[idx] = f2bf(o);
                    }
                }
            }
        }
}

// =====================================================================
// encoder v2: f16 MFMA, K-step 64, deep register prefetch, XOR-swizzled A-LDS.
// BM=32; wave w -> m-frag (w&1), col half (w>>1). grid (M/32, 1, 3)
__global__ __launch_bounds__(256)
void enc_f16v2(const float* __restrict__ text, const float* __restrict__ audio, const float* __restrict__ vision,
               const _Float16* __restrict__ Wf16,
               const float* __restrict__ bt, const float* __restrict__ ba, const float* __restrict__ bv,
               float* __restrict__ Cf, unsigned short* __restrict__ Cb, int M)
{
    __shared__ alignas(16) _Float16 Af[32 * 64];       // [row][c8^(row&7) chunks of 8]
    __shared__ alignas(16) _Float16 Bf[8 * 64 * 8];    // [kgroup][col][e]
    const int z = blockIdx.z;
    const float* A  = (z == 0) ? text : (z == 1) ? audio : vision;
    const _Float16* W = Wf16 + ((z == 0) ? 0 : (z == 1) ? 65536 : 98304);
    const float* bb = (z == 0) ? bt : (z == 1) ? ba : bv;
    const int K = (z == 1) ? 512 : 1024;

    const int t = threadIdx.x;
    const int w = t >> 6, l = t & 63;
    const int r16 = l & 15, kg = l >> 4;
    const int row0 = blockIdx.x * 32;
    const int mi = w & 1;
    const int ncol0 = (w >> 1) * 32;
    const int arow = t >> 3, ac8 = t & 7;     // A staging: 32 rows x 8 chunks(8 f32)
    const int bcol = t & 63, bw = t >> 6;     // B staging: wave bw stages k rows bw*16..+16

    const float* ap = A + (size_t)(row0 + arow) * K + ac8 * 8;
    const _Float16* wp = W + (size_t)(bw * 16) * 64 + bcol;

    float4 pa0 = *reinterpret_cast<const float4*>(ap);
    float4 pa1 = *reinterpret_cast<const float4*>(ap + 4);
    _Float16 pb[16];
#pragma unroll
    for (int j = 0; j < 16; ++j) pb[j] = wp[(size_t)j * 64];

    f32x4 acc[2] = {};
    const int asw = ac8 ^ (arow & 7);
    for (int k0 = 0; k0 < K; k0 += 64) {
        {
            half8v av;
            av[0] = (_Float16)pa0.x; av[1] = (_Float16)pa0.y;
            av[2] = (_Float16)pa0.z; av[3] = (_Float16)pa0.w;
            av[4] = (_Float16)pa1.x; av[5] = (_Float16)pa1.y;
            av[6] = (_Float16)pa1.z; av[7] = (_Float16)pa1.w;
            *reinterpret_cast<half8v*>(&Af[arow * 64 + asw * 8]) = av;
            half8v b0, b1;
#pragma unroll
            for (int j = 0; j < 8; ++j) { b0[j] = pb[j]; b1[j] = pb[8 + j]; }
            *reinterpret_cast<half8v*>(&Bf[(bw * 2) * 512 + bcol * 8]) = b0;
            *reinterpret_cast<half8v*>(&Bf[(bw * 2 + 1) * 512 + bcol * 8]) = b1;
        }
        __syncthreads();
        if (k0 + 64 < K) {
            pa0 = *reinterpret_cast<const float4*>(ap + k0 + 64);
            pa1 = *reinterpret_cast<const float4*>(ap + k0 + 68);
#pragma unroll
            for (int j = 0; j < 16; ++j) pb[j] = wp[(size_t)(k0 + 64 + j) * 64];
        }
        const int row = mi * 16 + r16;
        half8v afA = *reinterpret_cast<const half8v*>(&Af[row * 64 + (kg ^ (row & 7)) * 8]);
        half8v afB = *reinterpret_cast<const half8v*>(&Af[row * 64 + ((kg + 4) ^ (row & 7)) * 8]);
#pragma unroll
        for (int ni = 0; ni < 2; ++ni) {
            int cx = (ncol0 + ni * 16 + r16) * 8;
            half8v bf0 = *reinterpret_cast<const half8v*>(&Bf[kg * 512 + cx]);
            half8v bf1 = *reinterpret_cast<const half8v*>(&Bf[(kg + 4) * 512 + cx]);
            acc[ni] = __builtin_amdgcn_mfma_f32_16x16x32_f16(afA, bf0, acc[ni], 0, 0, 0);
            acc[ni] = __builtin_amdgcn_mfma_f32_16x16x32_f16(afB, bf1, acc[ni], 0, 0, 0);
        }
        __syncthreads();
    }
#pragma unroll
    for (int ni = 0; ni < 2; ++ni) {
        int col = ncol0 + ni * 16 + r16;
        float bvv = bb[col];
#pragma unroll
        for (int r = 0; r < 4; ++r) {
            int gr = row0 + mi * 16 + kg * 4 + r;
            if (gr < M) {
                float val = acc[ni][r] + bvv;
                size_t idx = (size_t)gr * 192 + z * 64 + col;
                Cf[idx] = val;
                Cb[idx] = f2bf(val);
            }
        }
    }
}

// =====================================================================
// one fused weight-pack kernel: enc f16 weights + all GAT-path bf16 weights + biases
// Wall layout (shorts): gc@0(36864) | g2@36864(36864) | g0@73728(196608) | r0@270336(98304) | g1@368640(98304)
// ball layout (f32):    g2@0(192) | g0@192(1024) | g1@1216(192)
__global__ void pack_all(const float* __restrict__ Wt, const float* __restrict__ Wa, const float* __restrict__ Wv,
                         const float* __restrict__ Wgc,
                         const float* __restrict__ Ws2, const float* __restrict__ Wd2, const float* __restrict__ Wr2,
                         const float* __restrict__ bs2, const float* __restrict__ bd2,
                         const float* __restrict__ Ws0, const float* __restrict__ Wd0,
                         const float* __restrict__ bs0, const float* __restrict__ bd0,
                         const float* __restrict__ Wr0,
                         const float* __restrict__ Ws1, const float* __restrict__ Wd1, const float* __restrict__ Wr1,
                         const float* __restrict__ bs1, const float* __restrict__ bd1,
                         _Float16* __restrict__ encW, unsigned short* __restrict__ Wall, float* __restrict__ ball)
{
    int gid = blockIdx.x * blockDim.x + threadIdx.x;
    if (gid < 163840) {
        float v = (gid < 65536) ? Wt[gid] : (gid < 98304) ? Wa[gid - 65536] : Wv[gid - 98304];
        encW[gid] = (_Float16)v;
    }
    if (gid < 36864) {
        Wall[gid] = f2bf(Wgc[gid]);
    } else if (gid < 73728) {
        int i = gid - 36864, k = i / 192, c = i - k * 192;
        float v = (c < 64) ? Ws2[k * 64 + c] : (c < 128) ? Wd2[k * 64 + c - 64] : Wr2[k * 64 + c - 128];
        Wall[gid] = f2bf(v);
    } else if (gid < 270336) {
        int i = gid - 73728, k = i >> 10, c = i & 1023;
        float v = (c < 512) ? Ws0[k * 512 + c] : Wd0[k * 512 + c - 512];
        Wall[gid] = f2bf(v);
    } else if (gid < 368640) {
        Wall[gid] = f2bf(Wr0[gid - 270336]);
    } else if (gid < 466944) {
        int i = gid - 368640, k = i / 192, c = i - k * 192;
        float v = (c < 64) ? Ws1[k * 64 + c] : (c < 128) ? Wd1[k * 64 + c - 64] : Wr1[k * 64 + c - 128];
        Wall[gid] = f2bf(v);
    } else if (gid < 468352) {
        int i = gid - 466944;
        float v;
        if (i < 192)       v = (i < 64) ? bs2[i] : (i < 128) ? bd2[i - 64] : 0.f;
        else if (i < 1216) { int j = i - 192; v = (j < 512) ? bs0[j] : bd0[j - 512]; }
        else               { int j = i - 1216; v = (j < 64) ? bs1[j] : (j < 128) ? bd1[j - 64] : 0.f; }
        ball[i] = v;
    }
}

// ---------------- graph preprocessing
__global__ void deg_kernel(const int* __restrict__ src, const int* __restrict__ dst,
                           int* degout, int* degin, int E)
{
    int e = blockIdx.x * blockDim.x + threadIdx.x;
    if (e < E) {
        atomicAdd(&degout[src[e]], 1);
        atomicAdd(&degin[dst[e]], 1);
    }
}

__global__ __launch_bounds__(1024)
void scan_kernel(const int* __restrict__ degin, int* __restrict__ rowstart, int n)
{
    __shared__ int part[1024];
    int t = threadIdx.x;
    int chunk = (n + 1023) / 1024;
    int s = 0;
    for (int i = 0; i < chunk; ++i) {
        int idx = t * chunk + i;
        if (idx < n) s += degin[idx];
    }
    part[t] = s;
    __syncthreads();
    for (int o = 1; o < 1024; o <<= 1) {
        int v = (t >= o) ? part[t - o] : 0;
        __syncthreads();
        part[t] += v;
        __syncthreads();
    }
    int run = (t > 0) ? part[t - 1] : 0;
    for (int i = 0; i < chunk; ++i) {
        int idx = t * chunk + i;
        if (idx < n) { rowstart[idx] = run; run += degin[idx]; }
    }
    if (t == 1023) rowstart[n] = part[1023];
}

__global__ void perm_kernel(const int* __restrict__ dst, const int* __restrict__ rowstart,
                            int* cursor, int* __restrict__ perm, int E)
{
    int e = blockIdx.x * blockDim.x + threadIdx.x;
    if (e < E) {
        int v = dst[e];
        int p = atomicAdd(&cursor[v], 1);
        perm[rowstart[v] + p] = e;
    }
}

__global__ void gather_src_kernel(const int* __restrict__ esrc, int* perm, int E)
{
    int i = blockIdx.x * blockDim.x + threadIdx.x;
    if (i < E) perm[i] = esrc[perm[i]];
}

__global__ void rs_kernel(const int* degout, const int* degin, float* rso, float* rsi, int n)
{
    int i = blockIdx.x * blockDim.x + threadIdx.x;
    if (i < n) {
        rso[i] = rsqrtf((float)max(degout[i], 1));
        rsi[i] = rsqrtf((float)max(degin[i], 1));
    }
}

// ---------------- LSTM
__global__ void lstm_pre(const float* __restrict__ x, const float* __restrict__ Wf,
                         const float* __restrict__ Wb,
                         const float* bf1, const float* bf2, const float* bb1, const float* bb2,
                         float* __restrict__ xWf, float* __restrict__ xWb, int n)
{
    int gid = blockIdx.x * blockDim.x + threadIdx.x;
    if (gid >= n * 32) return;
    int nn = gid >> 5, r = gid & 31, d = r >> 4, j = r & 15;
    const float* W = (d ? Wb : Wf) + j * 192;
    const float* xr = x + (size_t)nn * 192;
    float s = 0.f;
#pragma unroll 4
    for (int k = 0; k < 192; k += 4) {
        float4 xv = *reinterpret_cast<const float4*>(xr + k);
        float4 wv = *reinterpret_cast<const float4*>(W + k);
        s += xv.x * wv.x + xv.y * wv.y + xv.z * wv.z + xv.w * wv.w;
    }
    s += d ? (bb1[j] + bb2[j]) : (bf1[j] + bf2[j]);
    int b = nn / 120, tt = nn - b * 120;
    (d ? xWb : xWf)[((size_t)b * 16 + j) * 120 + tt] = s;
}

__device__ __forceinline__ float fsigm(float x) { return __fdividef(1.f, 1.f + __expf(-x)); }
__device__ __forceinline__ float ftanh(float x) { return 1.f - __fdividef(2.f, __expf(2.f * x) + 1.f); }

template<int DIR>
__device__ void lstm_chain(const float* __restrict__ xw, const float* __restrict__ whh,
                           float* __restrict__ newF, int b)
{
    int j = threadIdx.x & 15;
    int k = j & 3;
    float4 w = *reinterpret_cast<const float4*>(whh + j * 4);
    const float* xp = xw + ((size_t)b * 16 + j) * 120;
    float h0 = 0.f, h1 = 0.f, h2 = 0.f, h3 = 0.f, cst = 0.f;
    int tb0 = DIR ? 108 : 0;
    float4 a0 = *reinterpret_cast<const float4*>(xp + tb0);
    float4 a1 = *reinterpret_cast<const float4*>(xp + tb0 + 4);
    float4 a2 = *reinterpret_cast<const float4*>(xp + tb0 + 8);
    for (int ch = 0; ch < 10; ++ch) {
        float4 b0 = a0, b1 = a1, b2 = a2;
        if (ch < 9) {
            int nt = DIR ? (96 - ch * 12) : (12 + ch * 12);
            b0 = *reinterpret_cast<const float4*>(xp + nt);
            b1 = *reinterpret_cast<const float4*>(xp + nt + 4);
            b2 = *reinterpret_cast<const float4*>(xp + nt + 8);
        }
        float zz[12] = {a0.x, a0.y, a0.z, a0.w, a1.x, a1.y, a1.z, a1.w, a2.x, a2.y, a2.z, a2.w};
        int tbase = DIR ? (108 - ch * 12) : (ch * 12);
#pragma unroll
        for (int ii = 0; ii < 12; ++ii) {
            int idx = DIR ? (11 - ii) : ii;
            float z = zz[idx] + ((w.x * h0 + w.y * h1) + (w.z * h2 + w.w * h3));
            float zi = __shfl(z, k, 16);
            float zf = __shfl(z, k + 4, 16);
            float zg = __shfl(z, k + 8, 16);
            float zo = __shfl(z, k + 12, 16);
            float ig = fsigm(zi), fg = fsigm(zf), gg = ftanh(zg), og = fsigm(zo);
            cst = fg * cst + ig * gg;
            float hn = og * ftanh(cst);
            h0 = __shfl(hn, 0, 16); h1 = __shfl(hn, 1, 16);
            h2 = __shfl(hn, 2, 16); h3 = __shfl(hn, 3, 16);
            if (j < 4) newF[((size_t)b * 120 + tbase + idx) * 8 + DIR * 4 + j] = hn;
        }
        a0 = b0; a1 = b1; a2 = b2;
    }
}

__global__ __launch_bounds__(64)
void lstm_seq2(const float* __restrict__ xWf, const float* __restrict__ xWb,
               const float* __restrict__ Whhf, const float* __restrict__ Whhb,
               float* __restrict__ newF, int B)
{
    int sub = threadIdx.x >> 4;
    int chain = blockIdx.x * 4 + sub;
    if (chain >= 2 * B) return;
    int d = chain / B;
    int b = chain - d * B;
    if (d == 0) lstm_chain<0>(xWf, Whhf, newF, b);
    else        lstm_chain<1>(xWb, Whhb, newF, b);
}

// ---------------- GraphConv combine + L1 norm: 2-edge software pipeline
__global__ __launch_bounds__(256)
void gc_combine5(const float* __restrict__ stackFT, const unsigned short* __restrict__ hw,
                 const int* __restrict__ rowstart, const int* __restrict__ csrc,
                 const float* __restrict__ rs_in,
                 const float* __restrict__ b_gc, unsigned short* __restrict__ hB, int n)
{
    int v = blockIdx.x * 4 + (threadIdx.x >> 6);
    int l = threadIdx.x & 63;
    if (v >= n) return;
    int s0 = rowstart[v], s1 = rowstart[v + 1];
    float sum0 = 0.f, sum1 = 0.f, sum2 = 0.f;

    unsigned short a0 = 0, a1 = 0, a2 = 0, b0 = 0, b1 = 0, b2 = 0;
    auto LD = [&](int i, unsigned short& x0, unsigned short& x1, unsigned short& x2) {
        const unsigned short* hr = hw + (size_t)csrc[i] * 192 + l;
        x0 = hr[0]; x1 = hr[64]; x2 = hr[128];
    };
    int i = s0;
    if (i < s1) LD(i, a0, a1, a2);
    if (i + 1 < s1) LD(i + 1, b0, b1, b2);
    for (; i + 2 < s1; i += 2) {
        unsigned short n0, n1, n2, m0 = 0, m1 = 0, m2 = 0;
        LD(i + 2, n0, n1, n2);
        if (i + 3 < s1) LD(i + 3, m0, m1, m2);
        sum0 += bf2f(a0) + bf2f(b0);
        sum1 += bf2f(a1) + bf2f(b1);
        sum2 += bf2f(a2) + bf2f(b2);
        a0 = n0; a1 = n1; a2 = n2; b0 = m0; b1 = m1; b2 = m2;
    }
    if (i < s1) { sum0 += bf2f(a0); sum1 += bf2f(a1); sum2 += bf2f(a2); }
    if (i + 1 < s1) { sum0 += bf2f(b0); sum1 += bf2f(b1); sum2 += bf2f(b2); }

    float ri = rs_in[v];
    const float* sf = stackFT + (size_t)v * 192 + l;
    float v0 = 0.5f * (sf[0]   + sum0 * ri + b_gc[l]);
    float v1 = 0.5f * (sf[64]  + sum1 * ri + b_gc[l + 64]);
    float v2 = 0.5f * (sf[128] + sum2 * ri + b_gc[l + 128]);
    float r = fabsf(v0) + fabsf(v1) + fabsf(v2);
#pragma unroll
    for (int o = 32; o; o >>= 1) r += __shfl_xor(r, o);
    float inv = __fdividef(1.f, fmaxf(r, 1e-12f));
    unsigned short* hp = hB + (size_t)v * 192 + l;
    hp[0]   = f2bf(v0 * inv);
    hp[64]  = f2bf(v1 * inv);
    hp[128] = f2bf(v2 * inv);
}

// ---------------- GATv2 F=4 (HF=64): 16 lanes/node, 2-edge pipeline, fused epilogue
__global__ __launch_bounds__(256)
void gat_edge4c(const unsigned short* __restrict__ base, // [n,192] bf16 fs|fd|res
                const float* __restrict__ attn,
                const int* __restrict__ rowstart, const int* __restrict__ csrc,
                float* __restrict__ outp, int n)
{
    int v = blockIdx.x * 16 + (threadIdx.x >> 4);
    int l = threadIdx.x & 15;
    if (v >= n) return;
    float4 at = *reinterpret_cast<const float4*>(attn + l * 4);
    ushort4 fdu = *reinterpret_cast<const ushort4*>(base + (size_t)v * 192 + 64 + l * 4);
    float fd0 = bf2f(fdu.x), fd1 = bf2f(fdu.y), fd2 = bf2f(fdu.z), fd3 = bf2f(fdu.w);
    float ac0 = 0.f, ac1 = 0.f, ac2 = 0.f, ac3 = 0.f, dn = 0.f;
    int s0 = rowstart[v], s1 = rowstart[v + 1];

    auto LD = [&](int i) -> ushort4 {
        return *reinterpret_cast<const ushort4*>(base + (size_t)csrc[i] * 192 + l * 4);
    };
    auto ACC = [&](ushort4 su) {
        float s0f = bf2f(su.x), s1f = bf2f(su.y), s2f = bf2f(su.z), s3f = bf2f(su.w);
        float e0 = s0f + fd0; e0 = fmaxf(e0, 0.2f * e0);
        float e1 = s1f + fd1; e1 = fmaxf(e1, 0.2f * e1);
        float e2 = s2f + fd2; e2 = fmaxf(e2, 0.2f * e2);
        float e3 = s3f + fd3; e3 = fmaxf(e3, 0.2f * e3);
        float p = e0 * at.x + e1 * at.y + e2 * at.z + e3 * at.w;
        float ex = __expf(p);
        ac0 += ex * s0f; ac1 += ex * s1f; ac2 += ex * s2f; ac3 += ex * s3f;
        dn += ex;
    };
    const ushort4 zu = make_ushort4(0, 0, 0, 0);
    ushort4 c0 = zu, c1 = zu;
    int i = s0;
    if (i < s1) c0 = LD(i);
    if (i + 1 < s1) c1 = LD(i + 1);
    for (; i + 2 < s1; i += 2) {
        ushort4 n0 = LD(i + 2);
        ushort4 n1 = (i + 3 < s1) ? LD(i + 3) : zu;
        ACC(c0); ACC(c1);
        c0 = n0; c1 = n1;
    }
    if (i < s1) ACC(c0);
    if (i + 1 < s1) ACC(c1);

    ushort4 ru = *reinterpret_cast<const ushort4*>(base + (size_t)v * 192 + 128 + l * 4);
    float inv = (dn > 0.f) ? __fdividef(1.f, dn) : 0.f;
    float4 o;
    o.x = fmaxf(ac0 * inv + bf2f(ru.x), 0.f);
    o.y = fmaxf(ac1 * inv + bf2f(ru.y), 0.f);
    o.z = fmaxf(ac2 * inv + bf2f(ru.z), 0.f);
    o.w = fmaxf(ac3 * inv + bf2f(ru.w), 0.f);
    *reinterpret_cast<float4*>(outp + (size_t)v * 64 + l * 4) = o;
}

// ---------------- GATv2 F=32 (HF=512): one wave per node, 8 elems/lane, 2-edge pipeline
__global__ __launch_bounds__(256)
void gat_edge32b(const unsigned short* __restrict__ base,   // [n,1024] bf16 fs|fd
                 const float* __restrict__ attn,
                 const int* __restrict__ rowstart, const int* __restrict__ csrc,
                 float* __restrict__ num, float* __restrict__ den, int n)
{
    int v = blockIdx.x * 4 + (threadIdx.x >> 6);
    int l = threadIdx.x & 63;
    if (v >= n) return;
    float at[8];
    {
        float4 aA = *reinterpret_cast<const float4*>(attn + l * 8);
        float4 aB = *reinterpret_cast<const float4*>(attn + l * 8 + 4);
        at[0] = aA.x; at[1] = aA.y; at[2] = aA.z; at[3] = aA.w;
        at[4] = aB.x; at[5] = aB.y; at[6] = aB.z; at[7] = aB.w;
    }
    float fd[8];
    {
        short8 fdu = *reinterpret_cast<const short8*>(base + (size_t)v * 1024 + 512 + l * 8);
#pragma unroll
        for (int j = 0; j < 8; ++j) fd[j] = bf2f((unsigned short)fdu[j]);
    }
    float acc[8] = {};
    float dn = 0.f;
    int s0 = rowstart[v], s1 = rowstart[v + 1];

    auto LD = [&](int i) -> short8 {
        return *reinterpret_cast<const short8*>(base + (size_t)csrc[i] * 1024 + l * 8);
    };
    auto ACC = [&](short8 su) {
        float sf[8];
        float p = 0.f;
#pragma unroll
        for (int j = 0; j < 8; ++j) {
            sf[j] = bf2f((unsigned short)su[j]);
            float e = sf[j] + fd[j];
            e = fmaxf(e, 0.2f * e);
            p += e * at[j];
        }
        p += __shfl_xor(p, 1, 4);
        p += __shfl_xor(p, 2, 4);
        float ex = __expf(p);
#pragma unroll
        for (int j = 0; j < 8; ++j) acc[j] += ex * sf[j];
        dn += ex;
    };
    const short8 z8 = {0, 0, 0, 0, 0, 0, 0, 0};
    short8 c0 = z8, c1 = z8;
    int i = s0;
    if (i < s1) c0 = LD(i);
    if (i + 1 < s1) c1 = LD(i + 1);
    for (; i + 2 < s1; i += 2) {
        short8 n0 = LD(i + 2);
        short8 n1 = (i + 3 < s1) ? LD(i + 3) : z8;
        ACC(c0); ACC(c1);
        c0 = n0; c1 = n1;
    }
    if (i < s1) ACC(c0);
    if (i + 1 < s1) ACC(c1);

    float* np = num + (size_t)v * 512 + l * 8;
    *reinterpret_cast<float4*>(np)     = make_float4(acc[0], acc[1], acc[2], acc[3]);
    *reinterpret_cast<float4*>(np + 4) = make_float4(acc[4], acc[5], acc[6], acc[7]);
    if ((l & 3) == 0) den[(size_t)v * 16 + (l >> 2)] = dn;
}

// ---------------- final classifier
__global__ void final_lin(const float* __restrict__ h1, const float* __restrict__ newF,
                          const float* __restrict__ h3, const float* __restrict__ W,
                          const float* __restrict__ bias, float* __restrict__ out, int n)
{
    int gid = blockIdx.x * blockDim.x + threadIdx.x;
    if (gid >= n * 6) return;
    int v = gid / 6, o = gid - v * 6;
    float s = bias[o];
    const float* a = h1 + (size_t)v * 64;
#pragma unroll 8
    for (int r = 0; r < 64; ++r) s += a[r] * W[r * 6 + o];
    const float* b = newF + (size_t)v * 8;
#pragma unroll
    for (int r = 0; r < 8; ++r) s += b[r] * W[(64 + r) * 6 + o];
    const float* c = h3 + (size_t)v * 64;
#pragma unroll 8
    for (int r = 0; r < 64; ++r) s += c[r] * W[(72 + r) * 6 + o];
    out[gid] = s;
}

// ----------------------------------------------------------------------------
extern "C" void kernel_launch(void* const* d_in, const int* in_sizes, int n_in,
                              void* d_out, int out_size, void* d_ws, size_t ws_size,
                              hipStream_t stream)
{
    const float* text   = (const float*)d_in[0];
    const float* audio  = (const float*)d_in[1];
    const float* vision = (const float*)d_in[2];
    const int*   esrc   = (const int*)d_in[3];
    const int*   edst   = (const int*)d_in[4];
    const float* W_audio = (const float*)d_in[5];  const float* b_audio = (const float*)d_in[6];
    const float* W_vision= (const float*)d_in[7];  const float* b_vision= (const float*)d_in[8];
    const float* W_text  = (const float*)d_in[9];  const float* b_text  = (const float*)d_in[10];
    const float* Wih_f = (const float*)d_in[11]; const float* Whh_f = (const float*)d_in[12];
    const float* bih_f = (const float*)d_in[13]; const float* bhh_f = (const float*)d_in[14];
    const float* Wih_b = (const float*)d_in[15]; const float* Whh_b = (const float*)d_in[16];
    const float* bih_b = (const float*)d_in[17]; const float* bhh_b = (const float*)d_in[18];
    const float* W_gc  = (const float*)d_in[19]; const float* b_gc  = (const float*)d_in[20];
    const float* Wsrc2 = (const float*)d_in[21]; const float* bsrc2 = (const float*)d_in[22];
    const float* Wdst2 = (const float*)d_in[23]; const float* bdst2 = (const float*)d_in[24];
    const float* attn2 = (const float*)d_in[25]; const float* Wres2 = (const float*)d_in[26];
    const float* Wsrc0 = (const float*)d_in[27]; const float* bsrc0 = (const float*)d_in[28];
    const float* Wdst0 = (const float*)d_in[29]; const float* bdst0 = (const float*)d_in[30];
    const float* attn0 = (const float*)d_in[31]; const float* Wres0 = (const float*)d_in[32];
    const float* Wsrc1 = (const float*)d_in[33]; const float* bsrc1 = (const float*)d_in[34];
    const float* Wdst1 = (const float*)d_in[35]; const float* bdst1 = (const float*)d_in[36];
    const float* attn1 = (const float*)d_in[37]; const float* Wres1 = (const float*)d_in[38];
    const float* W_lin = (const float*)d_in[39]; const float* b_lin = (const float*)d_in[40];
    float* out = (float*)d_out;

    const int n = in_sizes[0] / 1024;   // 12000
    const int E = in_sizes[3];          // 192000
    const int B = n / 120;              // 100

    // ---- workspace carve (256B aligned)
    char* p = (char*)d_ws;
    auto alloc_f = [&](size_t cnt) { float* r = (float*)p; p += ((cnt * 4 + 255) / 256) * 256; return r; };
    auto alloc_h = [&](size_t cnt) { unsigned short* r = (unsigned short*)p; p += ((cnt * 2 + 255) / 256) * 256; return r; };
    auto alloc_i = [&](size_t cnt) { int* r = (int*)p; p += ((cnt * 4 + 255) / 256) * 256; return r; };
    float*          stackFT = alloc_f((size_t)n * 192);
    unsigned short* stackBF = alloc_h((size_t)n * 192);
    unsigned short* hbufBF  = alloc_h((size_t)n * 192);
    unsigned short* encW    = alloc_h(163840);
    float* xWf     = alloc_f((size_t)n * 16);
    float* xWb     = alloc_f((size_t)n * 16);
    float* newF    = alloc_f((size_t)n * 8);
    float* big0    = alloc_f((size_t)n * 512);
    float* big1    = alloc_f((size_t)n * 512);
    float* big2    = alloc_f((size_t)n * 512);
    float* den     = alloc_f((size_t)n * 16);
    float* h3      = alloc_f((size_t)n * 64);
    float* h1s     = alloc_f((size_t)n * 64);   // hosts packed weights until gat1 edge writes it
    float* rs_out  = alloc_f(n);
    float* rs_in   = alloc_f(n);
    int* zero_base = alloc_i((size_t)3 * n);
    int* degout = zero_base;
    int* degin  = zero_base + n;
    int* cursor = zero_base + 2 * n;
    int* rowstart = alloc_i((size_t)n + 1);
    int* perm     = alloc_i((size_t)E);
    if ((size_t)(p - (char*)d_ws) > ws_size) return;

    // packed weights live in h1s (dead until gat1 edge): 466944 shorts + 1408 floats
    unsigned short* Wall = (unsigned short*)h1s;
    float* ball = h1s + 240000;
    const unsigned short* Wp_gc = Wall;
    const unsigned short* Wp_g2 = Wall + 36864;
    const unsigned short* Wp_g0 = Wall + 73728;
    const unsigned short* Wp_r0 = Wall + 270336;
    const unsigned short* Wp_g1 = Wall + 368640;
    const float* bp_g2 = ball;
    const float* bp_g0 = ball + 192;
    const float* bp_g1 = ball + 1216;

    // ---- graph preprocessing + one fused weight-pack
    hipMemsetAsync(zero_base, 0, (size_t)3 * n * 4, stream);
    pack_all<<<(468352 + 255) / 256, 256, 0, stream>>>(
        W_text, W_audio, W_vision, W_gc,
        Wsrc2, Wdst2, Wres2, bsrc2, bdst2,
        Wsrc0, Wdst0, bsrc0, bdst0, Wres0,
        Wsrc1, Wdst1, Wres1, bsrc1, bdst1,
        (_Float16*)encW, Wall, ball);
    deg_kernel<<<(E + 255) / 256, 256, 0, stream>>>(esrc, edst, degout, degin, E);
    scan_kernel<<<1, 1024, 0, stream>>>(degin, rowstart, n);
    perm_kernel<<<(E + 255) / 256, 256, 0, stream>>>(edst, rowstart, cursor, perm, E);
    gather_src_kernel<<<(E + 255) / 256, 256, 0, stream>>>(esrc, perm, E);
    rs_kernel<<<(n + 255) / 256, 256, 0, stream>>>(degout, degin, rs_out, rs_in, n);
    const int* csrc = perm;

    auto gemm = [&](auto mf_tag, auto om_tag, const unsigned short* A, const unsigned short* Bm,
                    const float* bias, const float* rsc, void* Cp,
                    const float* fnum, const float* fden, int M, int Nb, int K, int ldc) {
        constexpr int MF = decltype(mf_tag)::value;
        constexpr int OM = decltype(om_tag)::value;
        dim3 grid((M + 64 * MF - 1) / (64 * MF), Nb / 64);
        gemm_v7<MF, OM><<<grid, 256, 0, stream>>>(A, Bm, bias, rsc, Cp, fnum, fden, M, Nb, K, ldc);
    };
    using I1 = std::integral_constant<int, 1>;
    using I2 = std::integral_constant<int, 2>;
    using O1 = std::integral_constant<int, 1>;
    using O2 = std::integral_constant<int, 2>;

    // ---- modality encoders (f16 MFMA, K-step 64) -> stackFT f32 + stackBF bf16
    {
        dim3 grid(n / 32, 1, 3);
        enc_f16v2<<<grid, 256, 0, stream>>>(text, audio, vision, (const _Float16*)encW,
                                            b_text, b_audio, b_vision, stackFT, stackBF, n);
    }

    // ---- BiLSTM
    lstm_pre<<<(n * 32 + 255) / 256, 256, 0, stream>>>(stackFT, Wih_f, Wih_b,
                                                       bih_f, bhh_f, bih_b, bhh_b, xWf, xWb, n);
    lstm_seq2<<<(2 * B + 3) / 4, 64, 0, stream>>>(xWf, xWb, Whh_f, Whh_b, newF, B);

    // ---- GraphConv imputation + L1 norm -> hbufBF (bf16)
    gemm(I1{}, O1{}, stackBF, Wp_gc, nullptr, rs_out, big0, nullptr, nullptr, n, 192, 192, 192);
    gc_combine5<<<(n + 3) / 4, 256, 0, stream>>>(stackFT, (const unsigned short*)big0,
                                                 rowstart, csrc, rs_in, b_gc, hbufBF, n);

    // ---- gat2: packed src|dst|res GEMM -> big0 bf16 [n,192], fused edge -> h3
    gemm(I1{}, O1{}, hbufBF, Wp_g2, bp_g2, nullptr, big0, nullptr, nullptr, n, 192, 192, 192);
    gat_edge4c<<<(n + 15) / 16, 256, 0, stream>>>((const unsigned short*)big0, attn2, rowstart, csrc, h3, n);

    // ---- gat0: packed src|dst GEMM -> big0 bf16 [n,1024]; edge -> big2/den;
    //            res GEMM with fused finalize -> big1 bf16 [n,512]
    gemm(I2{}, O1{}, hbufBF, Wp_g0, bp_g0, nullptr, big0, nullptr, nullptr, n, 1024, 192, 1024);
    gat_edge32b<<<(n + 3) / 4, 256, 0, stream>>>((const unsigned short*)big0, attn0, rowstart, csrc, big2, den, n);
    gemm(I1{}, O2{}, hbufBF, Wp_r0, nullptr, nullptr, big1, big2, den, n, 512, 192, 512);

    // ---- gat1: packed src|dst|res GEMM (A = big1 bf16 [n,512]) -> big0 bf16 [n,192], fused edge -> h1s
    gemm(I1{}, O1{}, (const unsigned short*)big1, Wp_g1, bp_g1, nullptr, big0, nullptr, nullptr, n, 192, 512, 192);
    gat_edge4c<<<(n + 15) / 16, 256, 0, stream>>>((const unsigned short*)big0, attn1, rowstart, csrc, h1s, n);

    // ---- final classifier
    final_lin<<<(n * 6 + 255) / 256, 256, 0, stream>>>(h1s, newF, h3, W_lin, b_lin, out, n);
}